// Round 3
// baseline (1266.489 us; speedup 1.0000x reference)
//
#include <hip/hip_runtime.h>
#include <hip/hip_bf16.h>
#include <math.h>

// D_MODEL=1024, D_INNER=2048, NHEADS=32, HEADDIM=64, CHUNK=64, B=4, L=4096
// C == ones collapses the state dim -> scalar scan per (h,p) channel.
// GEMMs: bf16x3 split MFMA (Ah*Bh + Ah*Bl + Al*Bh), fp32-equivalent.
//
// R3 changes:
//  - dt columns via tiny fp32 dot kernel (dtproj, ~10us) instead of a grid-32
//    old-structure MFMA GEMM (~50us latency-bound).
//  - gemm256: 2-phase K-tile with counted vmcnt (T4): phase A consumes
//    Ah/Bh/Bl (64 MFMA), phase B consumes Al (32 MFMA). Loads for tile k+1:
//    6 (Ah,Bh,Bl) issued at top of tile k, 2 (Al) at mid-tile. Waits:
//    mid vmcnt(6) [Al(k) done], end vmcnt(2) [AhBhBl(k+1) done] -- the vm
//    counter never drains to 0 in the main loop; raw s_barrier + asm waits.
//
// ws tiers (runtime-checked, deterministic):
//  small  ~100.3 MB : old layout, weights packed per batch, A split in-reg
//  +25.7  ~126.0 MB : weights packed once per call
//  +16.8  ~142.8 MB : u fragment-packed per batch -> gemm256 path enabled

typedef __attribute__((ext_vector_type(8))) short bf16x8;
typedef __attribute__((ext_vector_type(4))) float f32x4;

__device__ __forceinline__ float bf2f(unsigned short u) {
    union { float f; unsigned int i; } x; x.i = ((unsigned int)u) << 16; return x.f;
}
__device__ __forceinline__ unsigned short f2bf(float f) {  // RNE
    union { float f; unsigned int i; } x; x.f = f;
    unsigned int r = x.i + 0x7fffu + ((x.i >> 16) & 1u);
    return (unsigned short)(r >> 16);
}
__device__ __forceinline__ float softplusf(float x) {
    return (x > 20.f) ? x : log1pf(expf(x));
}
__device__ __forceinline__ float silu_mod(float x) {  // sigmoid(x)+0.1x per ref
    return 1.f / (1.f + expf(-x)) + 0.1f * x;
}
__device__ __forceinline__ void cvt_split2(float x, float y,
                                           unsigned int* hi, unsigned int* lo) {
    __hip_bfloat162 h2 = __float22bfloat162_rn(make_float2(x, y));
    unsigned int h; __builtin_memcpy(&h, &h2, 4);
    union { float f; unsigned int i; } fx, fy;
    fx.i = h << 16;
    fy.i = h & 0xffff0000u;
    __hip_bfloat162 l2 = __float22bfloat162_rn(make_float2(x - fx.f, y - fy.f));
    unsigned int l; __builtin_memcpy(&l, &l2, 4);
    *hi = h; *lo = l;
}
__device__ __forceinline__ void split4(float4 v, ushort4* h, ushort4* l) {
    unsigned short t;
    t = f2bf(v.x); h->x = t; l->x = f2bf(v.x - bf2f(t));
    t = f2bf(v.y); h->y = t; l->y = f2bf(v.y - bf2f(t));
    t = f2bf(v.z); h->z = t; l->z = f2bf(v.z - bf2f(t));
    t = f2bf(v.w); h->w = t; l->w = f2bf(v.w - bf2f(t));
}

// ---------------------------------------------------------------------------
// pack row-major fp32 -> fragment-order split bf16.
// thread t -> (tile = t>>(6+KCN_LOG), kc = (t>>6)&(KCN-1), lane = t&63):
//   data = src[tile*16 + (lane&15)][kc*32 + (lane>>4)*8 .. +8]
// REMAP (in_w): row<4096 -> row; 4096..4127 -> row+128 (dt cols); else zero.
// ---------------------------------------------------------------------------
template <int KCN_LOG, int REMAP>
__global__ __launch_bounds__(256) void pack_split(
    const float* __restrict__ src, int src_ld,
    unsigned short* __restrict__ h, unsigned short* __restrict__ l)
{
    int t = blockIdx.x * 256 + threadIdx.x;
    int lane = t & 63;
    int kc = (t >> 6) & ((1 << KCN_LOG) - 1);
    int tile = t >> (6 + KCN_LOG);
    int n = tile * 16 + (lane & 15);
    int k = kc * 32 + (lane >> 4) * 8;
    int sr = n;
    if (REMAP) sr = (n < 4096) ? n : (n < 4128 ? n + 128 : -1);
    float4 v0 = make_float4(0.f, 0.f, 0.f, 0.f), v1 = v0;
    if (sr >= 0) {
        const float* s = src + (size_t)sr * src_ld + k;
        v0 = *(const float4*)s;
        v1 = *(const float4*)(s + 4);
    }
    ushort4 h0, l0, h1, l1;
    split4(v0, &h0, &l0);
    split4(v1, &h1, &l1);
    size_t o = (size_t)t * 8;
    *(ushort4*)(h + o) = h0; *(ushort4*)(h + o + 4) = h1;
    *(ushort4*)(l + o) = l0; *(ushort4*)(l + o + 4) = l1;
}

// ---------------------------------------------------------------------------
// dtproj: dtraw[l,h] = dot(u[l,:], in_w[4224+h,:]) + in_b[4224+h]  (fp32).
// One thread per (l,h); 32 lanes share a u row (broadcast loads), weight
// working set 128 KB (L2-hot). Grid 512 x 256.
// ---------------------------------------------------------------------------
__global__ __launch_bounds__(256) void dtproj(
    const float* __restrict__ u, const float* __restrict__ in_w,
    const float* __restrict__ in_b, float* __restrict__ dtraw)
{
    int idx = blockIdx.x * 256 + threadIdx.x;
    int l = idx >> 5, h = idx & 31;
    const float* ur = u + (size_t)l * 1024;
    const float* wr = in_w + (size_t)(4224 + h) * 1024;
    float s0 = 0.f, s1 = 0.f, s2 = 0.f, s3 = 0.f;
#pragma unroll 4
    for (int k = 0; k < 1024; k += 4) {
        float4 a = *(const float4*)(ur + k);
        float4 b = *(const float4*)(wr + k);
        s0 += a.x * b.x; s1 += a.y * b.y;
        s2 += a.z * b.z; s3 += a.w * b.w;
    }
    dtraw[idx] = (s0 + s1) + (s2 + s3) + in_b[4224 + h];
}

// ---------------------------------------------------------------------------
// LDS-free bf16x3 MFMA NT-GEMM (old structure) — kept for fallback tiers.
// ---------------------------------------------------------------------------
template <int ASRC, int OUT, int KDIM, int KSPLIT, int NOFF>
__global__ __launch_bounds__(256, 2) void mfma_gemm(
    const float* __restrict__ Af,
    const unsigned short* __restrict__ Aph, const unsigned short* __restrict__ Apl,
    const unsigned short* __restrict__ Bph, const unsigned short* __restrict__ Bpl,
    const float* __restrict__ bias,
    float* __restrict__ oz, float* __restrict__ oxc,
    float* __restrict__ dtraw, float* __restrict__ outC)
{
    constexpr int KCN = KDIM / 32;       // layout stride (total K chunks)
    constexpr int KCNL = KCN / KSPLIT;   // chunks this block iterates
    const int g = blockIdx.x;
    const int ks = (KSPLIT > 1) ? (g >> 8) : 0;
    const int gg = (KSPLIT > 1) ? (g & 255) : g;
    const int m0 = ((gg & 7) * 4 + ((gg >> 3) & 3)) * 128;
    const int n0 = (gg >> 5) * 128 + NOFF;
    const int tid = threadIdx.x;
    const int lane = tid & 63, w = tid >> 6;
    const int wm = w & 1, wn = w >> 1;
    const int fr = lane & 15, q = lane >> 4;
    const size_t koff = (size_t)ks * KCNL * 512;  // shorts

    const unsigned short* bhp[4];
    const unsigned short* blp[4];
#pragma unroll
    for (int nt = 0; nt < 4; nt++) {
        size_t c = ((size_t)((n0 >> 4) + wn * 4 + nt) * KCN * 64 + lane) * 8 + koff;
        bhp[nt] = Bph + c;
        blp[nt] = Bpl + c;
    }
    const float* afp[4];
    const unsigned short* ahp[4];
    const unsigned short* alp[4];
#pragma unroll
    for (int mt = 0; mt < 4; mt++) {
        if (ASRC == 0) {
            afp[mt] = Af + (size_t)(m0 + wm * 64 + mt * 16 + fr) * KDIM + q * 8
                         + (size_t)ks * (KDIM / KSPLIT);
        } else {
            size_t c = ((size_t)((m0 >> 4) + wm * 4 + mt) * KCN * 64 + lane) * 8 + koff;
            ahp[mt] = Aph + c;
            alp[mt] = Apl + c;
        }
    }

    f32x4 acc[4][4];
#pragma unroll
    for (int i = 0; i < 4; i++)
#pragma unroll
        for (int j = 0; j < 4; j++) acc[i][j] = (f32x4){0.f, 0.f, 0.f, 0.f};

    bf16x8 bh[2][4], bl[2][4], ah[2][4], al[2][4];
    float4 af0[2][4], af1[2][4];

#define LOAD_STEP(B)                                                          \
    {                                                                         \
        _Pragma("unroll") for (int nt = 0; nt < 4; nt++) {                    \
            bh[B][nt] = *(const bf16x8*)bhp[nt];                              \
            bl[B][nt] = *(const bf16x8*)blp[nt];                              \
            bhp[nt] += 512; blp[nt] += 512;                                   \
        }                                                                     \
        _Pragma("unroll") for (int mt = 0; mt < 4; mt++) {                    \
            if (ASRC == 1) {                                                  \
                ah[B][mt] = *(const bf16x8*)ahp[mt];                          \
                al[B][mt] = *(const bf16x8*)alp[mt];                          \
                ahp[mt] += 512; alp[mt] += 512;                               \
            } else {                                                          \
                af0[B][mt] = *(const float4*)afp[mt];                         \
                af1[B][mt] = *(const float4*)(afp[mt] + 4);                   \
                afp[mt] += 32;                                                \
            }                                                                 \
        }                                                                     \
    }

#define MFMA_STEP(B)                                                          \
    {                                                                         \
        bf16x8 xah[4], xal[4];                                                \
        _Pragma("unroll") for (int mt = 0; mt < 4; mt++) {                    \
            if (ASRC == 1) {                                                  \
                xah[mt] = ah[B][mt]; xal[mt] = al[B][mt];                     \
            } else {                                                          \
                union { bf16x8 v; unsigned int u[4]; } H, L;                  \
                cvt_split2(af0[B][mt].x, af0[B][mt].y, &H.u[0], &L.u[0]);     \
                cvt_split2(af0[B][mt].z, af0[B][mt].w, &H.u[1], &L.u[1]);     \
                cvt_split2(af1[B][mt].x, af1[B][mt].y, &H.u[2], &L.u[2]);     \
                cvt_split2(af1[B][mt].z, af1[B][mt].w, &H.u[3], &L.u[3]);     \
                xah[mt] = H.v; xal[mt] = L.v;                                 \
            }                                                                 \
        }                                                                     \
        _Pragma("unroll") for (int mt = 0; mt < 4; mt++)                      \
            _Pragma("unroll") for (int nt = 0; nt < 4; nt++)                  \
                acc[mt][nt] = __builtin_amdgcn_mfma_f32_16x16x32_bf16(        \
                    xah[mt], bh[B][nt], acc[mt][nt], 0, 0, 0);                \
        _Pragma("unroll") for (int mt = 0; mt < 4; mt++)                      \
            _Pragma("unroll") for (int nt = 0; nt < 4; nt++)                  \
                acc[mt][nt] = __builtin_amdgcn_mfma_f32_16x16x32_bf16(        \
                    xah[mt], bl[B][nt], acc[mt][nt], 0, 0, 0);                \
        _Pragma("unroll") for (int mt = 0; mt < 4; mt++)                      \
            _Pragma("unroll") for (int nt = 0; nt < 4; nt++)                  \
                acc[mt][nt] = __builtin_amdgcn_mfma_f32_16x16x32_bf16(        \
                    xal[mt], bh[B][nt], acc[mt][nt], 0, 0, 0);                \
    }

    LOAD_STEP(0);
    for (int kc = 0; kc + 2 < KCNL; kc += 2) {
        LOAD_STEP(1);
        MFMA_STEP(0);
        LOAD_STEP(0);
        MFMA_STEP(1);
    }
    LOAD_STEP(1);
    MFMA_STEP(0);
    MFMA_STEP(1);
#undef LOAD_STEP
#undef MFMA_STEP

    // epilogue: D[row=q*4+reg][col=fr] per 16x16 tile
#pragma unroll
    for (int nt = 0; nt < 4; nt++) {
        int jn = n0 + wn * 64 + nt * 16 + fr;
        if (OUT == 0 && jn >= 4128) continue;
        float bv = 0.f;
        if (OUT == 0) bv = bias[jn < 4096 ? jn : jn + 128];
#pragma unroll
        for (int mt = 0; mt < 4; mt++) {
#pragma unroll
            for (int reg = 0; reg < 4; reg++) {
                int rm = m0 + wm * 64 + mt * 16 + q * 4 + reg;
                float v = acc[mt][nt][reg] + bv;
                if (OUT == 0) {
                    if (jn < 2048)      oz[(size_t)rm * 2048 + jn] = v;
                    else if (jn < 4096) oxc[(size_t)rm * 2048 + (jn - 2048)] = v;
                    else                dtraw[(size_t)rm * 32 + (jn - 4096)] = v;
                } else {
                    float* dst = (KSPLIT == 1 || ks == 0) ? outC : oz;
                    dst[(size_t)rm * 1024 + jn] = v;
                }
            }
        }
    }
}

// ---------------------------------------------------------------------------
// gemm256: 256x256 tile, 512 threads (8 waves, 2M x 4N), BK=32 split-bf16.
// LDS 128KB: 2 buffers x {Ah,Al,Bh,Bl} x 16 tiles x 512 shorts, fragment
// order (ds_read_b128 stride-1 across lanes: conflict-free, no swizzle).
// 2-phase K-tile + counted vmcnt (T4):
//   phase A: ah x (Bh,Bl)  [64 MFMA]  needs Ah,Bh,Bl of tile k
//   phase B: al x Bh       [32 MFMA]  needs Al of tile k
// Loads for k+1: 6 (Ah,Bh,Bl) at top of k, 2 (Al) at mid.  Waits:
//   mid: vmcnt(6) -> my Al(k) done; end: vmcnt(2) -> my AhBhBl(k+1) done.
// vm counter never drains to 0 in the main loop.  Raw s_barrier + asm waits
// (compiler memory fences both sides).
// OUT 0: in_proj main (N=4096): z / xc + bias. OUT 1: out_proj split-K=4.
// ---------------------------------------------------------------------------
template <int KCN, int NT, int OUT>
__global__ __launch_bounds__(512, 2) void gemm256(
    const unsigned short* __restrict__ Aph, const unsigned short* __restrict__ Apl,
    const unsigned short* __restrict__ Bph, const unsigned short* __restrict__ Bpl,
    const float* __restrict__ bias,
    float* __restrict__ oz, float* __restrict__ oxc,
    float* __restrict__ outC,
    float* __restrict__ p1, float* __restrict__ p2, float* __restrict__ p3)
{
    __shared__ unsigned short smem[65536];  // 128 KiB
    const int g = blockIdx.x;
    int mb, nb, kt0;
    float* dst = outC;
    if (OUT == 0) {
        const int xcd = g & 7, loc = g >> 3;     // XCD x owns n-blocks {2x,2x+1}
        nb = xcd * 2 + (loc & 1);
        mb = loc >> 1;
        kt0 = 0;
    } else {
        const int ks = g >> 6, loc = g & 63;
        mb = loc & 15; nb = loc >> 4; kt0 = ks * NT;
        dst = (ks == 0) ? outC : (ks == 1 ? p1 : (ks == 2 ? p2 : p3));
    }
    const int tid = threadIdx.x;
    const int lane = tid & 63, w = tid >> 6;
    const int wm = w & 1, wn = w >> 1;
    const int fr = lane & 15, q = lane >> 4;

    // per-wave staging: tiles {2w, 2w+1} of each operand-half (8 gload_lds)
    const unsigned short* gp[8];
    {
        const int tA0 = mb * 16 + 2 * w;
        const int tB0 = nb * 16 + 2 * w;
        size_t a0 = ((size_t)tA0 * KCN + kt0) * 512 + lane * 8;
        size_t a1 = ((size_t)(tA0 + 1) * KCN + kt0) * 512 + lane * 8;
        size_t b0 = ((size_t)tB0 * KCN + kt0) * 512 + lane * 8;
        size_t b1 = ((size_t)(tB0 + 1) * KCN + kt0) * 512 + lane * 8;
        gp[0] = Aph + a0; gp[1] = Aph + a1;
        gp[2] = Apl + a0; gp[3] = Apl + a1;
        gp[4] = Bph + b0; gp[5] = Bph + b1;
        gp[6] = Bpl + b0; gp[7] = Bpl + b1;
    }
    int ldso[8];
    {
        const int t0 = 2 * w * 512, t1 = t0 + 512;
        ldso[0] = t0;          ldso[1] = t1;          // Ah
        ldso[2] = 8192 + t0;   ldso[3] = 8192 + t1;   // Al
        ldso[4] = 16384 + t0;  ldso[5] = 16384 + t1;  // Bh
        ldso[6] = 24576 + t0;  ldso[7] = 24576 + t1;  // Bl
    }

#define ISSUE(i, bp)                                                          \
    __builtin_amdgcn_global_load_lds(                                         \
        (const __attribute__((address_space(1))) unsigned int*)gp[i],         \
        (__attribute__((address_space(3))) unsigned int*)((bp) + ldso[i]),    \
        16, 0, 0);                                                            \
    gp[i] += 512;

    // 6 loads: Ah pair + Bh pair + Bl pair (phase-A data of next tile)
#define STAGE6(BUF)                                                           \
    {                                                                         \
        unsigned short* bp = smem + (BUF) * 32768;                            \
        ISSUE(0, bp) ISSUE(1, bp) ISSUE(4, bp) ISSUE(5, bp)                   \
        ISSUE(6, bp) ISSUE(7, bp)                                             \
    }
    // 2 loads: Al pair (phase-B data of next tile)
#define STAGE2(BUF)                                                           \
    {                                                                         \
        unsigned short* bp = smem + (BUF) * 32768;                            \
        ISSUE(2, bp) ISSUE(3, bp)                                             \
    }

#define CFENCE asm volatile("" ::: "memory")

    f32x4 acc[8][4];
#pragma unroll
    for (int i = 0; i < 8; i++)
#pragma unroll
        for (int j = 0; j < 4; j++) acc[i][j] = (f32x4){0.f, 0.f, 0.f, 0.f};

    // prologue: full tile 0 into buffer 0, drain, publish
    {
        unsigned short* bp = smem;
        ISSUE(0, bp) ISSUE(1, bp) ISSUE(2, bp) ISSUE(3, bp)
        ISSUE(4, bp) ISSUE(5, bp) ISSUE(6, bp) ISSUE(7, bp)
    }
    asm volatile("s_waitcnt vmcnt(0)" ::: "memory");
    __builtin_amdgcn_s_barrier();
    CFENCE;

    for (int kt = 0; kt < NT; ++kt) {
        const int cur = kt & 1;
        const unsigned short* sb = smem + cur * 32768;
        if (kt + 1 < NT) STAGE6(cur ^ 1);
        // ---- phase A: Bh/Bl frags + ah sweep (64 MFMA) ----
        bf16x8 Bh_[4], Bl_[4];
#pragma unroll
        for (int nt = 0; nt < 4; nt++) {
            Bh_[nt] = *(const bf16x8*)(sb + 16384 + (wn * 4 + nt) * 512 + lane * 8);
            Bl_[nt] = *(const bf16x8*)(sb + 24576 + (wn * 4 + nt) * 512 + lane * 8);
        }
#pragma unroll
        for (int mt = 0; mt < 8; mt++) {
            bf16x8 ah = *(const bf16x8*)(sb + (wm * 8 + mt) * 512 + lane * 8);
            __builtin_amdgcn_s_setprio(1);
#pragma unroll
            for (int nt = 0; nt < 4; nt++)
                acc[mt][nt] = __builtin_amdgcn_mfma_f32_16x16x32_bf16(
                    ah, Bh_[nt], acc[mt][nt], 0, 0, 0);
#pragma unroll
            for (int nt = 0; nt < 4; nt++)
                acc[mt][nt] = __builtin_amdgcn_mfma_f32_16x16x32_bf16(
                    ah, Bl_[nt], acc[mt][nt], 0, 0, 0);
            __builtin_amdgcn_s_setprio(0);
        }
        // ---- mid barrier: publish Al(kt) ----
        if (kt + 1 < NT) {
            asm volatile("s_waitcnt vmcnt(6)" ::: "memory");
        } else {
            asm volatile("s_waitcnt vmcnt(0)" ::: "memory");
        }
        __builtin_amdgcn_s_barrier();
        CFENCE;
        if (kt + 1 < NT) STAGE2(cur ^ 1);
        // ---- phase B: al sweep (32 MFMA) ----
#pragma unroll
        for (int mt = 0; mt < 8; mt++) {
            bf16x8 al = *(const bf16x8*)(sb + 8192 + (wm * 8 + mt) * 512 + lane * 8);
            __builtin_amdgcn_s_setprio(1);
#pragma unroll
            for (int nt = 0; nt < 4; nt++)
                acc[mt][nt] = __builtin_amdgcn_mfma_f32_16x16x32_bf16(
                    al, Bh_[nt], acc[mt][nt], 0, 0, 0);
            __builtin_amdgcn_s_setprio(0);
        }
        // ---- end barrier: publish AhBhBl(kt+1) ----
        if (kt + 1 < NT) {
            asm volatile("s_waitcnt vmcnt(2)" ::: "memory");
            __builtin_amdgcn_s_barrier();
            CFENCE;
        }
    }
#undef ISSUE
#undef STAGE6
#undef STAGE2
#undef CFENCE

    // epilogue: D[row=q*4+reg][col=fr] per 16x16 tile
    const int m0 = mb * 256, n0 = nb * 256;
#pragma unroll
    for (int nt = 0; nt < 4; nt++) {
        const int jn = n0 + wn * 64 + nt * 16 + fr;
        float bv = 0.f;
        if (OUT == 0) bv = bias[jn];
#pragma unroll
        for (int mt = 0; mt < 8; mt++) {
#pragma unroll
            for (int reg = 0; reg < 4; reg++) {
                const int rm = m0 + wm * 128 + mt * 16 + q * 4 + reg;
                float v = acc[mt][nt][reg] + bv;
                if (OUT == 0) {
                    if (jn < 2048) oz[(size_t)rm * 2048 + jn] = v;
                    else           oxc[(size_t)rm * 2048 + (jn - 2048)] = v;
                } else {
                    dst[(size_t)rm * 1024 + jn] = v;
                }
            }
        }
    }
}

// ---------------------------------------------------------------------------
// split-K reductions.
// ---------------------------------------------------------------------------
__global__ __launch_bounds__(256) void addOut(
    float* __restrict__ dst, const float* __restrict__ part)
{
    size_t i = ((size_t)blockIdx.x * 256 + threadIdx.x) * 4;
    float4 a = *(const float4*)(dst + i);
    float4 b = *(const float4*)(part + i);
    a.x += b.x; a.y += b.y; a.z += b.z; a.w += b.w;
    *(float4*)(dst + i) = a;
}

__global__ __launch_bounds__(256) void addOut4(
    float* __restrict__ dst, const float* __restrict__ a,
    const float* __restrict__ b, const float* __restrict__ c)
{
    size_t i = ((size_t)blockIdx.x * 256 + threadIdx.x) * 4;
    float4 d = *(const float4*)(dst + i);
    float4 x = *(const float4*)(a + i);
    float4 y = *(const float4*)(b + i);
    float4 zz = *(const float4*)(c + i);
    d.x += x.x + y.x + zz.x;
    d.y += x.y + y.y + zz.y;
    d.z += x.z + y.z + zz.z;
    d.w += x.w + y.w + zz.w;
    *(float4*)(dst + i) = d;
}

// ---------------------------------------------------------------------------
// scanA: one batch. Per (h, chunk) block, 64 threads (p). conv4 + silu' +
// softplus(dt) + decay cumsum + 64-step local scan. xc/ylocal fp32.
// ---------------------------------------------------------------------------
__global__ __launch_bounds__(64) void scanA(
    const float* __restrict__ xc,
    const float* __restrict__ dtraw, const float* __restrict__ reward,
    const float* __restrict__ conv_w, const float* __restrict__ conv_b,
    const float* __restrict__ dt_bias, const float* __restrict__ A_log,
    const float* __restrict__ bw, const float* __restrict__ bb,
    float* __restrict__ ylocal,
    float* __restrict__ decay, float* __restrict__ Fb, float* __restrict__ Eb)
{
    const int blk = blockIdx.x;        // h*64 + t
    const int t = blk & 63;
    const int h = blk >> 6;
    const int p = threadIdx.x;
    const int l0 = t * 64;

    __shared__ float xs[67][65];
    __shared__ float gbuf[64], ebuf[64], dtbuf[64];
    __shared__ float cum63;

    float v1 = bw[p] + bw[p + 64];
    float v2 = bb[p] + bb[p + 64];
#pragma unroll
    for (int o = 32; o > 0; o >>= 1) {
        v1 += __shfl_down(v1, o, 64);
        v2 += __shfl_down(v2, o, 64);
    }
    const float sbw = __shfl(v1, 0, 64);
    const float sbb = __shfl(v2, 0, 64);

    const int l = l0 + p;
    const float dt = softplusf(dtraw[(size_t)l * 32 + h] + dt_bias[h]);
    const float a = -expf(A_log[h]) * dt;
    float cum = a;
#pragma unroll
    for (int o = 1; o < 64; o <<= 1) {
        float uo = __shfl_up(cum, o, 64);
        if (p >= o) cum += uo;
    }
    decay[(size_t)l * 32 + h] = expf(cum);
    gbuf[p] = reward[l] * sbw + sbb;
    ebuf[p] = expf(a);
    dtbuf[p] = dt;
    if (p == 63) cum63 = cum;

    const int c = h * 64 + p;
    for (int r = 0; r < 67; r++) {
        int ls = l0 - 3 + r;
        xs[r][p] = (ls >= 0) ? xc[(size_t)ls * 2048 + c] : 0.f;
    }
    __syncthreads();

    const float w0 = conv_w[c * 4 + 0], w1 = conv_w[c * 4 + 1],
                w2 = conv_w[c * 4 + 2], w3 = conv_w[c * 4 + 3];
    const float cb = conv_b[c];
    float y = 0.f;
    float* outp = ylocal + (size_t)l0 * 2048 + c;
#pragma unroll 4
    for (int i = 0; i < 64; i++) {
        float v = cb + xs[i][p] * w0 + xs[i + 1][p] * w1 +
                  xs[i + 2][p] * w2 + xs[i + 3][p] * w3;
        float xdt = silu_mod(v) * dtbuf[i];
        y = y * ebuf[i] + gbuf[i] * xdt;
        outp[(size_t)i * 2048] = y;
    }
    Fb[((size_t)h * 64 + t) * 64 + p] = y;
    if (p == 0) Eb[(size_t)h * 64 + t] = expf(cum63);
}

// ---------------------------------------------------------------------------
// scanB: cross-chunk scan. 32 blocks x 64 threads.
// ---------------------------------------------------------------------------
__global__ __launch_bounds__(64) void scanB(
    const float* __restrict__ Fb, const float* __restrict__ Eb,
    float* __restrict__ Sprev)
{
    int idx = blockIdx.x * blockDim.x + threadIdx.x;  // 2048
    int p = idx & 63;
    int h = idx >> 6;
    int base = h * 64;
    float S = 0.f;
#pragma unroll 8
    for (int t = 0; t < 64; t++) {
        Sprev[(size_t)(base + t) * 64 + p] = S;
        S = S * Eb[base + t] + Fb[(size_t)(base + t) * 64 + p];
    }
}

// ---------------------------------------------------------------------------
// passC: y = (ylocal + S*decay) * silu_mod(z), emitted split bf16 directly in
// gemm2's A fragment-packed order (KCN=64).
// ---------------------------------------------------------------------------
__global__ __launch_bounds__(256) void passC(
    const float* __restrict__ yl, const float* __restrict__ z,
    const float* __restrict__ Sprev, const float* __restrict__ decay,
    unsigned short* __restrict__ yph, unsigned short* __restrict__ ypl)
{
    size_t idx = ((size_t)blockIdx.x * 256 + threadIdx.x) * 4;
    int row = (int)(idx >> 11);
    int cc = (int)(idx & 2047);
    int t = row >> 6;
    int h = cc >> 6, p = cc & 63;
    float4 av = *(const float4*)(yl + idx);
    float4 bvz = *(const float4*)(z + idx);
    float4 sv = *(const float4*)(Sprev + ((size_t)(h * 64 + t)) * 64 + p);
    float d = decay[(size_t)row * 32 + h];
    float4 yv;
    yv.x = (av.x + sv.x * d) * silu_mod(bvz.x);
    yv.y = (av.y + sv.y * d) * silu_mod(bvz.y);
    yv.z = (av.z + sv.z * d) * silu_mod(bvz.z);
    yv.w = (av.w + sv.w * d) * silu_mod(bvz.w);
    ushort4 hv, lv;
    split4(yv, &hv, &lv);
    size_t chunk = (((size_t)(row >> 4) * 64 + (cc >> 5)) * 64) + ((cc >> 3) & 3) * 16 + (row & 15);
    size_t o = chunk * 8 + (cc & 7);
    *(ushort4*)(yph + o) = hv;
    *(ushort4*)(ypl + o) = lv;
}

// ---------------------------------------------------------------------------
extern "C" void kernel_launch(void* const* d_in, const int* in_sizes, int n_in,
                              void* d_out, int out_size, void* d_ws, size_t ws_size,
                              hipStream_t stream)
{
    const float* u       = (const float*)d_in[0];
    const float* reward  = (const float*)d_in[1];
    const float* in_w    = (const float*)d_in[2];
    const float* in_b    = (const float*)d_in[3];
    const float* conv_w  = (const float*)d_in[4];
    const float* conv_b  = (const float*)d_in[5];
    const float* bw      = (const float*)d_in[6];
    const float* bb      = (const float*)d_in[7];
    const float* dt_bias = (const float*)d_in[8];
    const float* A_log   = (const float*)d_in[9];
    const float* out_w   = (const float*)d_in[10];
    float* out = (float*)d_out;

    char* p = (char*)d_ws;
    const size_t SEG = (size_t)4096 * 2048 * 4;  // 33,554,432 B
    float* z = (float*)p;                              // R0 (-> split-K partials)
    float* xc = (float*)(p + SEG);                     // R1 (-> ypacked)
    unsigned short* yph = (unsigned short*)(p + SEG);
    unsigned short* ypl = yph + (size_t)4096 * 2048;
    char* R2 = p + 2 * SEG;                            // R2
    float* ylocal = (float*)R2;
    char* ps = p + 3 * SEG;                            // tail
    float* dtraw = (float*)ps;                 ps += (size_t)4096 * 32 * 4;
    float* decay = (float*)ps;                 ps += (size_t)4096 * 32 * 4;
    float* Fb    = (float*)ps;                 ps += (size_t)32 * 64 * 64 * 4;
    float* Eb    = (float*)ps;                 ps += (size_t)32 * 64 * 4;
    float* Sprev = (float*)ps;                 ps += (size_t)32 * 64 * 64 * 4;

    const size_t W1PN = (size_t)264 * 32 * 64 * 8;  // shorts per w1 half
    const size_t W2PN = (size_t)64 * 64 * 64 * 8;   // shorts per w2 half
    const size_t UPN  = (size_t)256 * 32 * 64 * 8;  // shorts per u half
    size_t used_small = (size_t)(ps - (char*)d_ws);
    bool wonce = ws_size >= used_small + 2 * sizeof(unsigned short) * (W1PN + W2PN);
    bool upack = ws_size >= used_small + 2 * sizeof(unsigned short) * (W1PN + W2PN + UPN);

    unsigned short *w1ph, *w1pl, *w2ph, *w2pl, *uph = nullptr, *upl = nullptr;
    if (wonce) {
        w1ph = (unsigned short*)ps;
        w1pl = w1ph + W1PN;
        w2ph = w1pl + W1PN;
        w2pl = w2ph + W2PN;
        pack_split<5, 1><<<2112, 256, 0, stream>>>(in_w, 1024, w1ph, w1pl);
        pack_split<6, 0><<<1024, 256, 0, stream>>>(out_w, 2048, w2ph, w2pl);
        if (upack) {
            uph = w2pl + W2PN;
            upl = uph + UPN;
        }
    } else {
        w1ph = (unsigned short*)R2;
        w1pl = w1ph + W1PN;
        w2ph = (unsigned short*)R2;
        w2pl = w2ph + W2PN;
    }

    for (int b = 0; b < 4; b++) {
        const float* ub = u + (size_t)b * 4096 * 1024;
        const float* rb = reward + (size_t)b * 4096;
        float* ob = out + (size_t)b * 4096 * 1024;

        if (!wonce)
            pack_split<5, 1><<<2112, 256, 0, stream>>>(in_w, 1024, w1ph, w1pl);
        // 1) in_proj
        if (upack) {
            pack_split<5, 0><<<2048, 256, 0, stream>>>(ub, 1024, uph, upl);
            // main N=4096: 256 blocks = 1/CU, LDS-staged 256^2, counted vmcnt
            gemm256<32, 32, 0><<<256, 512, 0, stream>>>(
                uph, upl, w1ph, w1pl, in_b, z, xc,
                nullptr, nullptr, nullptr, nullptr);
            // dt columns (32): fp32 dot kernel
            dtproj<<<512, 256, 0, stream>>>(ub, in_w, in_b, dtraw);
        } else {
            mfma_gemm<0, 0, 1024, 1, 0><<<1056, 256, 0, stream>>>(
                ub, nullptr, nullptr, w1ph, w1pl, in_b, z, xc, dtraw, nullptr);
        }
        // 2) conv + local chunk scan (xc -> ylocal in R2)
        scanA<<<2048, 64, 0, stream>>>(xc, dtraw, rb, conv_w, conv_b,
                                       dt_bias, A_log, bw, bb,
                                       ylocal, decay, Fb, Eb);
        // 3) cross-chunk scan
        scanB<<<32, 64, 0, stream>>>(Fb, Eb, Sprev);
        // 4) gate + carried state -> y fragment-packed into R1
        passC<<<8192, 256, 0, stream>>>(ylocal, z, Sprev, decay, yph, ypl);
        if (!wonce)
            pack_split<6, 0><<<1024, 256, 0, stream>>>(out_w, 2048, w2ph, w2pl);
        // 5) out_proj
        if (upack) {
            // split-K=4: 256 blocks; partials into dead z (R0) + ylocal (R2)
            float* pA = z;
            float* pB = z + (size_t)4096 * 1024;
            float* pC = ylocal;
            gemm256<64, 16, 1><<<256, 512, 0, stream>>>(
                yph, ypl, w2ph, w2pl, nullptr, nullptr, nullptr,
                ob, pA, pB, pC);
            addOut4<<<4096, 256, 0, stream>>>(ob, pA, pB, pC);
        } else {
            mfma_gemm<1, 1, 2048, 2, 0><<<512, 256, 0, stream>>>(
                nullptr, yph, ypl, w2ph, w2pl, nullptr,
                z, nullptr, nullptr, ob);
            addOut<<<4096, 256, 0, stream>>>(ob, z);
        }
    }
}

// Round 4
// 1099.746 us; speedup vs baseline: 1.1516x; 1.1516x over previous
//
#include <hip/hip_runtime.h>
#include <hip/hip_bf16.h>
#include <math.h>

// D_MODEL=1024, D_INNER=2048, NHEADS=32, HEADDIM=64, CHUNK=64, B=4, L=4096
// C == ones collapses the state dim -> scalar scan per (h,p) channel.
// GEMMs: bf16x3 split MFMA (Ah*Bh + Ah*Bl + Al*Bh), fp32-equivalent.
//
// R4 changes:
//  - gemm256: fine 4-phase K-tile schedule (m201-style): per phase
//    {2 gload_lds -> 4 ds_read -> barrier -> lgkm0 -> 24 MFMA -> barrier};
//    B frags read in phase 0 and held; vmcnt(2) once per tile (never 0
//    mid-loop). 8 barriers/tile, setprio around each MFMA cluster.
//  - dtproj2: dt weights pre-transposed to [k4][h][4] (pack_dtw, once/call)
//    -> fully coalesced 512B half-wave reads (R3's dtproj was a 32-way
//    gather, est. 60-100us/batch -> the R3 regression).
//
// ws tiers (runtime-checked, deterministic):
//  small  ~100.3 MB : old layout, weights packed per batch, A split in-reg
//  +25.7  ~126.0 MB : weights packed once per call
//  +16.9  ~142.9 MB : u fragment-packed per batch -> gemm256 + dtproj2 path

typedef __attribute__((ext_vector_type(8))) short bf16x8;
typedef __attribute__((ext_vector_type(4))) float f32x4;

__device__ __forceinline__ float bf2f(unsigned short u) {
    union { float f; unsigned int i; } x; x.i = ((unsigned int)u) << 16; return x.f;
}
__device__ __forceinline__ unsigned short f2bf(float f) {  // RNE
    union { float f; unsigned int i; } x; x.f = f;
    unsigned int r = x.i + 0x7fffu + ((x.i >> 16) & 1u);
    return (unsigned short)(r >> 16);
}
__device__ __forceinline__ float softplusf(float x) {
    return (x > 20.f) ? x : log1pf(expf(x));
}
__device__ __forceinline__ float silu_mod(float x) {  // sigmoid(x)+0.1x per ref
    return 1.f / (1.f + expf(-x)) + 0.1f * x;
}
__device__ __forceinline__ void cvt_split2(float x, float y,
                                           unsigned int* hi, unsigned int* lo) {
    __hip_bfloat162 h2 = __float22bfloat162_rn(make_float2(x, y));
    unsigned int h; __builtin_memcpy(&h, &h2, 4);
    union { float f; unsigned int i; } fx, fy;
    fx.i = h << 16;
    fy.i = h & 0xffff0000u;
    __hip_bfloat162 l2 = __float22bfloat162_rn(make_float2(x - fx.f, y - fy.f));
    unsigned int l; __builtin_memcpy(&l, &l2, 4);
    *hi = h; *lo = l;
}
__device__ __forceinline__ void split4(float4 v, ushort4* h, ushort4* l) {
    unsigned short t;
    t = f2bf(v.x); h->x = t; l->x = f2bf(v.x - bf2f(t));
    t = f2bf(v.y); h->y = t; l->y = f2bf(v.y - bf2f(t));
    t = f2bf(v.z); h->z = t; l->z = f2bf(v.z - bf2f(t));
    t = f2bf(v.w); h->w = t; l->w = f2bf(v.w - bf2f(t));
}

// ---------------------------------------------------------------------------
// pack row-major fp32 -> fragment-order split bf16.
// thread t -> (tile = t>>(6+KCN_LOG), kc = (t>>6)&(KCN-1), lane = t&63):
//   data = src[tile*16 + (lane&15)][kc*32 + (lane>>4)*8 .. +8]
// REMAP (in_w): row<4096 -> row; 4096..4127 -> row+128 (dt cols); else zero.
// ---------------------------------------------------------------------------
template <int KCN_LOG, int REMAP>
__global__ __launch_bounds__(256) void pack_split(
    const float* __restrict__ src, int src_ld,
    unsigned short* __restrict__ h, unsigned short* __restrict__ l)
{
    int t = blockIdx.x * 256 + threadIdx.x;
    int lane = t & 63;
    int kc = (t >> 6) & ((1 << KCN_LOG) - 1);
    int tile = t >> (6 + KCN_LOG);
    int n = tile * 16 + (lane & 15);
    int k = kc * 32 + (lane >> 4) * 8;
    int sr = n;
    if (REMAP) sr = (n < 4096) ? n : (n < 4128 ? n + 128 : -1);
    float4 v0 = make_float4(0.f, 0.f, 0.f, 0.f), v1 = v0;
    if (sr >= 0) {
        const float* s = src + (size_t)sr * src_ld + k;
        v0 = *(const float4*)s;
        v1 = *(const float4*)(s + 4);
    }
    ushort4 h0, l0, h1, l1;
    split4(v0, &h0, &l0);
    split4(v1, &h1, &l1);
    size_t o = (size_t)t * 8;
    *(ushort4*)(h + o) = h0; *(ushort4*)(h + o + 4) = h1;
    *(ushort4*)(l + o) = l0; *(ushort4*)(l + o + 4) = l1;
}

// ---------------------------------------------------------------------------
// pack_dtw: dt weight rows 4224..4255 of in_w -> dtw[k4][h][4] fp32 (128 KB),
// so dtproj2's 32-lane h-groups read contiguous 512B. Once per call.
// ---------------------------------------------------------------------------
__global__ __launch_bounds__(256) void pack_dtw(
    const float* __restrict__ in_w, float* __restrict__ dtw)
{
    int o = blockIdx.x * 256 + threadIdx.x;   // 32768
    int k4 = o >> 7, rem = o & 127;
    int h = rem >> 2, r = rem & 3;
    dtw[o] = in_w[(size_t)(4224 + h) * 1024 + k4 * 4 + r];
}

// ---------------------------------------------------------------------------
// dtproj2: dtraw[l,h] = dot(u[l,:], dt_w[h,:]) + in_b[4224+h], fp32.
// Thread (l,h); w reads coalesced via packed layout; u float4 broadcast
// per half-wave. Grid 512 x 256.
// ---------------------------------------------------------------------------
__global__ __launch_bounds__(256) void dtproj2(
    const float* __restrict__ u, const float* __restrict__ dtw,
    const float* __restrict__ in_b, float* __restrict__ dtraw)
{
    int idx = blockIdx.x * 256 + threadIdx.x;
    int l = idx >> 5, h = idx & 31;
    const float* ur = u + (size_t)l * 1024;
    const float* wp = dtw + h * 4;
    float s0 = 0.f, s1 = 0.f, s2 = 0.f, s3 = 0.f;
#pragma unroll 4
    for (int k4 = 0; k4 < 256; k4++) {
        float4 a = *(const float4*)(ur + k4 * 4);
        float4 b = *(const float4*)(wp + (size_t)k4 * 128);
        s0 += a.x * b.x; s1 += a.y * b.y;
        s2 += a.z * b.z; s3 += a.w * b.w;
    }
    dtraw[idx] = (s0 + s1) + (s2 + s3) + in_b[4224 + h];
}

// ---------------------------------------------------------------------------
// LDS-free bf16x3 MFMA NT-GEMM (old structure) — kept for fallback tiers.
// ---------------------------------------------------------------------------
template <int ASRC, int OUT, int KDIM, int KSPLIT, int NOFF>
__global__ __launch_bounds__(256, 2) void mfma_gemm(
    const float* __restrict__ Af,
    const unsigned short* __restrict__ Aph, const unsigned short* __restrict__ Apl,
    const unsigned short* __restrict__ Bph, const unsigned short* __restrict__ Bpl,
    const float* __restrict__ bias,
    float* __restrict__ oz, float* __restrict__ oxc,
    float* __restrict__ dtraw, float* __restrict__ outC)
{
    constexpr int KCN = KDIM / 32;       // layout stride (total K chunks)
    constexpr int KCNL = KCN / KSPLIT;   // chunks this block iterates
    const int g = blockIdx.x;
    const int ks = (KSPLIT > 1) ? (g >> 8) : 0;
    const int gg = (KSPLIT > 1) ? (g & 255) : g;
    const int m0 = ((gg & 7) * 4 + ((gg >> 3) & 3)) * 128;
    const int n0 = (gg >> 5) * 128 + NOFF;
    const int tid = threadIdx.x;
    const int lane = tid & 63, w = tid >> 6;
    const int wm = w & 1, wn = w >> 1;
    const int fr = lane & 15, q = lane >> 4;
    const size_t koff = (size_t)ks * KCNL * 512;  // shorts

    const unsigned short* bhp[4];
    const unsigned short* blp[4];
#pragma unroll
    for (int nt = 0; nt < 4; nt++) {
        size_t c = ((size_t)((n0 >> 4) + wn * 4 + nt) * KCN * 64 + lane) * 8 + koff;
        bhp[nt] = Bph + c;
        blp[nt] = Bpl + c;
    }
    const float* afp[4];
    const unsigned short* ahp[4];
    const unsigned short* alp[4];
#pragma unroll
    for (int mt = 0; mt < 4; mt++) {
        if (ASRC == 0) {
            afp[mt] = Af + (size_t)(m0 + wm * 64 + mt * 16 + fr) * KDIM + q * 8
                         + (size_t)ks * (KDIM / KSPLIT);
        } else {
            size_t c = ((size_t)((m0 >> 4) + wm * 4 + mt) * KCN * 64 + lane) * 8 + koff;
            ahp[mt] = Aph + c;
            alp[mt] = Apl + c;
        }
    }

    f32x4 acc[4][4];
#pragma unroll
    for (int i = 0; i < 4; i++)
#pragma unroll
        for (int j = 0; j < 4; j++) acc[i][j] = (f32x4){0.f, 0.f, 0.f, 0.f};

    bf16x8 bh[2][4], bl[2][4], ah[2][4], al[2][4];
    float4 af0[2][4], af1[2][4];

#define LOAD_STEP(B)                                                          \
    {                                                                         \
        _Pragma("unroll") for (int nt = 0; nt < 4; nt++) {                    \
            bh[B][nt] = *(const bf16x8*)bhp[nt];                              \
            bl[B][nt] = *(const bf16x8*)blp[nt];                              \
            bhp[nt] += 512; blp[nt] += 512;                                   \
        }                                                                     \
        _Pragma("unroll") for (int mt = 0; mt < 4; mt++) {                    \
            if (ASRC == 1) {                                                  \
                ah[B][mt] = *(const bf16x8*)ahp[mt];                          \
                al[B][mt] = *(const bf16x8*)alp[mt];                          \
                ahp[mt] += 512; alp[mt] += 512;                               \
            } else {                                                          \
                af0[B][mt] = *(const float4*)afp[mt];                         \
                af1[B][mt] = *(const float4*)(afp[mt] + 4);                   \
                afp[mt] += 32;                                                \
            }                                                                 \
        }                                                                     \
    }

#define MFMA_STEP(B)                                                          \
    {                                                                         \
        bf16x8 xah[4], xal[4];                                                \
        _Pragma("unroll") for (int mt = 0; mt < 4; mt++) {                    \
            if (ASRC == 1) {                                                  \
                xah[mt] = ah[B][mt]; xal[mt] = al[B][mt];                     \
            } else {                                                          \
                union { bf16x8 v; unsigned int u[4]; } H, L;                  \
                cvt_split2(af0[B][mt].x, af0[B][mt].y, &H.u[0], &L.u[0]);     \
                cvt_split2(af0[B][mt].z, af0[B][mt].w, &H.u[1], &L.u[1]);     \
                cvt_split2(af1[B][mt].x, af1[B][mt].y, &H.u[2], &L.u[2]);     \
                cvt_split2(af1[B][mt].z, af1[B][mt].w, &H.u[3], &L.u[3]);     \
                xah[mt] = H.v; xal[mt] = L.v;                                 \
            }                                                                 \
        }                                                                     \
        _Pragma("unroll") for (int mt = 0; mt < 4; mt++)                      \
            _Pragma("unroll") for (int nt = 0; nt < 4; nt++)                  \
                acc[mt][nt] = __builtin_amdgcn_mfma_f32_16x16x32_bf16(        \
                    xah[mt], bh[B][nt], acc[mt][nt], 0, 0, 0);                \
        _Pragma("unroll") for (int mt = 0; mt < 4; mt++)                      \
            _Pragma("unroll") for (int nt = 0; nt < 4; nt++)                  \
                acc[mt][nt] = __builtin_amdgcn_mfma_f32_16x16x32_bf16(        \
                    xah[mt], bl[B][nt], acc[mt][nt], 0, 0, 0);                \
        _Pragma("unroll") for (int mt = 0; mt < 4; mt++)                      \
            _Pragma("unroll") for (int nt = 0; nt < 4; nt++)                  \
                acc[mt][nt] = __builtin_amdgcn_mfma_f32_16x16x32_bf16(        \
                    xal[mt], bh[B][nt], acc[mt][nt], 0, 0, 0);                \
    }

    LOAD_STEP(0);
    for (int kc = 0; kc + 2 < KCNL; kc += 2) {
        LOAD_STEP(1);
        MFMA_STEP(0);
        LOAD_STEP(0);
        MFMA_STEP(1);
    }
    LOAD_STEP(1);
    MFMA_STEP(0);
    MFMA_STEP(1);
#undef LOAD_STEP
#undef MFMA_STEP

    // epilogue: D[row=q*4+reg][col=fr] per 16x16 tile
#pragma unroll
    for (int nt = 0; nt < 4; nt++) {
        int jn = n0 + wn * 64 + nt * 16 + fr;
        if (OUT == 0 && jn >= 4128) continue;
        float bv = 0.f;
        if (OUT == 0) bv = bias[jn < 4096 ? jn : jn + 128];
#pragma unroll
        for (int mt = 0; mt < 4; mt++) {
#pragma unroll
            for (int reg = 0; reg < 4; reg++) {
                int rm = m0 + wm * 64 + mt * 16 + q * 4 + reg;
                float v = acc[mt][nt][reg] + bv;
                if (OUT == 0) {
                    if (jn < 2048)      oz[(size_t)rm * 2048 + jn] = v;
                    else if (jn < 4096) oxc[(size_t)rm * 2048 + (jn - 2048)] = v;
                    else                dtraw[(size_t)rm * 32 + (jn - 4096)] = v;
                } else {
                    float* dst = (KSPLIT == 1 || ks == 0) ? outC : oz;
                    dst[(size_t)rm * 1024 + jn] = v;
                }
            }
        }
    }
}

// ---------------------------------------------------------------------------
// gemm256: 256x256 tile, 512 threads (8 waves, 2M x 4N), BK=32 split-bf16.
// LDS 128KB: 2 buffers x {Ah,Al,Bh,Bl} x 16 tiles x 512 shorts, fragment
// order (ds_read_b128 stride-1 across lanes: conflict-free, no swizzle).
// Fine 4-phase K-tile schedule (m201-style). Phase p handles mt {2p,2p+1},
// all 3 split passes (24 MFMA). B frags read in phase 0, held in regs.
// Per phase: {2 gload_lds(k+1) -> ds_read A-frags -> s_barrier -> lgkm0 ->
// setprio(1) 24 MFMA setprio(0) -> s_barrier}. vm wait once per tile at
// phase 0: vmcnt(2) (the 2 just-issued loads stay in flight; never 0 in
// the main loop). Ledger: writes to buf[cur^1] only after prior tile's
// trailing barrier (reads forced complete by each wave's lgkm0); reads of
// buf[cur] only after phase-0's vm-wait + barrier.
// OUT 0: in_proj main (N=4096): z / xc + bias. OUT 1: out_proj split-K=4.
// ---------------------------------------------------------------------------
template <int KCN, int NT, int OUT>
__global__ __launch_bounds__(512, 2) void gemm256(
    const unsigned short* __restrict__ Aph, const unsigned short* __restrict__ Apl,
    const unsigned short* __restrict__ Bph, const unsigned short* __restrict__ Bpl,
    const float* __restrict__ bias,
    float* __restrict__ oz, float* __restrict__ oxc,
    float* __restrict__ outC,
    float* __restrict__ p1, float* __restrict__ p2, float* __restrict__ p3)
{
    __shared__ unsigned short smem[65536];  // 128 KiB
    const int g = blockIdx.x;
    int mb, nb, kt0;
    float* dst = outC;
    if (OUT == 0) {
        const int xcd = g & 7, loc = g >> 3;     // XCD x owns n-blocks {2x,2x+1}
        nb = xcd * 2 + (loc & 1);
        mb = loc >> 1;
        kt0 = 0;
    } else {
        const int ks = g >> 6, loc = g & 63;
        mb = loc & 15; nb = loc >> 4; kt0 = ks * NT;
        dst = (ks == 0) ? outC : (ks == 1 ? p1 : (ks == 2 ? p2 : p3));
    }
    const int tid = threadIdx.x;
    const int lane = tid & 63, w = tid >> 6;
    const int wm = w & 1, wn = w >> 1;
    const int fr = lane & 15, q = lane >> 4;

    // per-wave staging: tiles {2w, 2w+1} of each operand-half (8 gload_lds)
    const unsigned short* gp[8];
    {
        const int tA0 = mb * 16 + 2 * w;
        const int tB0 = nb * 16 + 2 * w;
        size_t a0 = ((size_t)tA0 * KCN + kt0) * 512 + lane * 8;
        size_t a1 = ((size_t)(tA0 + 1) * KCN + kt0) * 512 + lane * 8;
        size_t b0 = ((size_t)tB0 * KCN + kt0) * 512 + lane * 8;
        size_t b1 = ((size_t)(tB0 + 1) * KCN + kt0) * 512 + lane * 8;
        gp[0] = Aph + a0; gp[1] = Aph + a1;
        gp[2] = Apl + a0; gp[3] = Apl + a1;
        gp[4] = Bph + b0; gp[5] = Bph + b1;
        gp[6] = Bpl + b0; gp[7] = Bpl + b1;
    }
    int ldso[8];
    {
        const int t0 = 2 * w * 512, t1 = t0 + 512;
        ldso[0] = t0;          ldso[1] = t1;          // Ah
        ldso[2] = 8192 + t0;   ldso[3] = 8192 + t1;   // Al
        ldso[4] = 16384 + t0;  ldso[5] = 16384 + t1;  // Bh
        ldso[6] = 24576 + t0;  ldso[7] = 24576 + t1;  // Bl
    }

#define ISSUE(i, bp)                                                          \
    __builtin_amdgcn_global_load_lds(                                         \
        (const __attribute__((address_space(1))) unsigned int*)gp[i],         \
        (__attribute__((address_space(3))) unsigned int*)((bp) + ldso[i]),    \
        16, 0, 0);                                                            \
    gp[i] += 512;

#define CFENCE asm volatile("" ::: "memory")

#define MFMA1(av, bv, MT, NTI)                                                \
    acc[MT][NTI] = __builtin_amdgcn_mfma_f32_16x16x32_bf16(                   \
        av, bv, acc[MT][NTI], 0, 0, 0)

#define CLUSTER24(MT0, MT1, A0H, A1H, A0L, A1L)                               \
    __builtin_amdgcn_s_setprio(1);                                            \
    _Pragma("unroll") for (int nt = 0; nt < 4; nt++)                          \
        MFMA1(A0H, Bh_[nt], MT0, nt);                                         \
    _Pragma("unroll") for (int nt = 0; nt < 4; nt++)                          \
        MFMA1(A1H, Bh_[nt], MT1, nt);                                         \
    _Pragma("unroll") for (int nt = 0; nt < 4; nt++)                          \
        MFMA1(A0H, Bl_[nt], MT0, nt);                                         \
    _Pragma("unroll") for (int nt = 0; nt < 4; nt++)                          \
        MFMA1(A1H, Bl_[nt], MT1, nt);                                         \
    _Pragma("unroll") for (int nt = 0; nt < 4; nt++)                          \
        MFMA1(A0L, Bh_[nt], MT0, nt);                                         \
    _Pragma("unroll") for (int nt = 0; nt < 4; nt++)                          \
        MFMA1(A1L, Bh_[nt], MT1, nt);                                         \
    __builtin_amdgcn_s_setprio(0);

    // phases 1..3: issue 2 loads, read 4 A-frags (data already published at
    // this tile's phase-0 barrier), barrier, lgkm0, 24 MFMA, barrier.
#define PHASE_TAIL(GI0, GI1, MT0, MT1)                                        \
    {                                                                         \
        if (pre) { ISSUE(GI0, bpn) ISSUE(GI1, bpn) }                          \
        bf16x8 a0h = *(const bf16x8*)(sb + (wm * 8 + MT0) * 512 + lane * 8);  \
        bf16x8 a1h = *(const bf16x8*)(sb + (wm * 8 + MT1) * 512 + lane * 8);  \
        bf16x8 a0l = *(const bf16x8*)(sb + 8192 + (wm * 8 + MT0) * 512 + lane * 8); \
        bf16x8 a1l = *(const bf16x8*)(sb + 8192 + (wm * 8 + MT1) * 512 + lane * 8); \
        __builtin_amdgcn_s_barrier(); CFENCE;                                 \
        asm volatile("s_waitcnt lgkmcnt(0)" ::: "memory");                    \
        __builtin_amdgcn_sched_barrier(0);                                    \
        CLUSTER24(MT0, MT1, a0h, a1h, a0l, a1l)                               \
        __builtin_amdgcn_s_barrier(); CFENCE;                                 \
    }

    f32x4 acc[8][4];
#pragma unroll
    for (int i = 0; i < 8; i++)
#pragma unroll
        for (int j = 0; j < 4; j++) acc[i][j] = (f32x4){0.f, 0.f, 0.f, 0.f};

    // prologue: full tile 0 into buffer 0, drain, publish
    {
        unsigned short* bp = smem;
        ISSUE(0, bp) ISSUE(1, bp) ISSUE(2, bp) ISSUE(3, bp)
        ISSUE(4, bp) ISSUE(5, bp) ISSUE(6, bp) ISSUE(7, bp)
    }
    asm volatile("s_waitcnt vmcnt(0)" ::: "memory");
    __builtin_amdgcn_s_barrier();
    CFENCE;

    bf16x8 Bh_[4], Bl_[4];

    for (int kt = 0; kt < NT; ++kt) {
        const int cur = kt & 1;
        const unsigned short* sb = smem + cur * 32768;
        unsigned short* bpn = smem + (cur ^ 1) * 32768;
        const bool pre = (kt + 1 < NT);

        // ---- phase 0: publish buf[cur]; B frags + mt{0,1} ----
        if (pre) {
            ISSUE(4, bpn) ISSUE(5, bpn)
            asm volatile("s_waitcnt vmcnt(2)" ::: "memory");
        } else {
            asm volatile("s_waitcnt vmcnt(0)" ::: "memory");
        }
        __builtin_amdgcn_s_barrier(); CFENCE;
        {
#pragma unroll
            for (int nt = 0; nt < 4; nt++) {
                Bh_[nt] = *(const bf16x8*)(sb + 16384 + (wn * 4 + nt) * 512 + lane * 8);
                Bl_[nt] = *(const bf16x8*)(sb + 24576 + (wn * 4 + nt) * 512 + lane * 8);
            }
            bf16x8 a0h = *(const bf16x8*)(sb + (wm * 8 + 0) * 512 + lane * 8);
            bf16x8 a1h = *(const bf16x8*)(sb + (wm * 8 + 1) * 512 + lane * 8);
            bf16x8 a0l = *(const bf16x8*)(sb + 8192 + (wm * 8 + 0) * 512 + lane * 8);
            bf16x8 a1l = *(const bf16x8*)(sb + 8192 + (wm * 8 + 1) * 512 + lane * 8);
            asm volatile("s_waitcnt lgkmcnt(0)" ::: "memory");
            __builtin_amdgcn_sched_barrier(0);
            CLUSTER24(0, 1, a0h, a1h, a0l, a1l)
        }
        __builtin_amdgcn_s_barrier(); CFENCE;

        PHASE_TAIL(6, 7, 2, 3)
        PHASE_TAIL(0, 1, 4, 5)
        PHASE_TAIL(2, 3, 6, 7)
    }
#undef ISSUE
#undef CFENCE
#undef MFMA1
#undef CLUSTER24
#undef PHASE_TAIL

    // epilogue: D[row=q*4+reg][col=fr] per 16x16 tile
    const int m0 = mb * 256, n0 = nb * 256;
#pragma unroll
    for (int nt = 0; nt < 4; nt++) {
        const int jn = n0 + wn * 64 + nt * 16 + fr;
        float bv = 0.f;
        if (OUT == 0) bv = bias[jn];
#pragma unroll
        for (int mt = 0; mt < 8; mt++) {
#pragma unroll
            for (int reg = 0; reg < 4; reg++) {
                const int rm = m0 + wm * 128 + mt * 16 + q * 4 + reg;
                float v = acc[mt][nt][reg] + bv;
                if (OUT == 0) {
                    if (jn < 2048) oz[(size_t)rm * 2048 + jn] = v;
                    else           oxc[(size_t)rm * 2048 + (jn - 2048)] = v;
                } else {
                    dst[(size_t)rm * 1024 + jn] = v;
                }
            }
        }
    }
}

// ---------------------------------------------------------------------------
// split-K reductions.
// ---------------------------------------------------------------------------
__global__ __launch_bounds__(256) void addOut(
    float* __restrict__ dst, const float* __restrict__ part)
{
    size_t i = ((size_t)blockIdx.x * 256 + threadIdx.x) * 4;
    float4 a = *(const float4*)(dst + i);
    float4 b = *(const float4*)(part + i);
    a.x += b.x; a.y += b.y; a.z += b.z; a.w += b.w;
    *(float4*)(dst + i) = a;
}

__global__ __launch_bounds__(256) void addOut4(
    float* __restrict__ dst, const float* __restrict__ a,
    const float* __restrict__ b, const float* __restrict__ c)
{
    size_t i = ((size_t)blockIdx.x * 256 + threadIdx.x) * 4;
    float4 d = *(const float4*)(dst + i);
    float4 x = *(const float4*)(a + i);
    float4 y = *(const float4*)(b + i);
    float4 zz = *(const float4*)(c + i);
    d.x += x.x + y.x + zz.x;
    d.y += x.y + y.y + zz.y;
    d.z += x.z + y.z + zz.z;
    d.w += x.w + y.w + zz.w;
    *(float4*)(dst + i) = d;
}

// ---------------------------------------------------------------------------
// scanA: one batch. Per (h, chunk) block, 64 threads (p). conv4 + silu' +
// softplus(dt) + decay cumsum + 64-step local scan. xc/ylocal fp32.
// ---------------------------------------------------------------------------
__global__ __launch_bounds__(64) void scanA(
    const float* __restrict__ xc,
    const float* __restrict__ dtraw, const float* __restrict__ reward,
    const float* __restrict__ conv_w, const float* __restrict__ conv_b,
    const float* __restrict__ dt_bias, const float* __restrict__ A_log,
    const float* __restrict__ bw, const float* __restrict__ bb,
    float* __restrict__ ylocal,
    float* __restrict__ decay, float* __restrict__ Fb, float* __restrict__ Eb)
{
    const int blk = blockIdx.x;        // h*64 + t
    const int t = blk & 63;
    const int h = blk >> 6;
    const int p = threadIdx.x;
    const int l0 = t * 64;

    __shared__ float xs[67][65];
    __shared__ float gbuf[64], ebuf[64], dtbuf[64];
    __shared__ float cum63;

    float v1 = bw[p] + bw[p + 64];
    float v2 = bb[p] + bb[p + 64];
#pragma unroll
    for (int o = 32; o > 0; o >>= 1) {
        v1 += __shfl_down(v1, o, 64);
        v2 += __shfl_down(v2, o, 64);
    }
    const float sbw = __shfl(v1, 0, 64);
    const float sbb = __shfl(v2, 0, 64);

    const int l = l0 + p;
    const float dt = softplusf(dtraw[(size_t)l * 32 + h] + dt_bias[h]);
    const float a = -expf(A_log[h]) * dt;
    float cum = a;
#pragma unroll
    for (int o = 1; o < 64; o <<= 1) {
        float uo = __shfl_up(cum, o, 64);
        if (p >= o) cum += uo;
    }
    decay[(size_t)l * 32 + h] = expf(cum);
    gbuf[p] = reward[l] * sbw + sbb;
    ebuf[p] = expf(a);
    dtbuf[p] = dt;
    if (p == 63) cum63 = cum;

    const int c = h * 64 + p;
    for (int r = 0; r < 67; r++) {
        int ls = l0 - 3 + r;
        xs[r][p] = (ls >= 0) ? xc[(size_t)ls * 2048 + c] : 0.f;
    }
    __syncthreads();

    const float w0 = conv_w[c * 4 + 0], w1 = conv_w[c * 4 + 1],
                w2 = conv_w[c * 4 + 2], w3 = conv_w[c * 4 + 3];
    const float cb = conv_b[c];
    float y = 0.f;
    float* outp = ylocal + (size_t)l0 * 2048 + c;
#pragma unroll 4
    for (int i = 0; i < 64; i++) {
        float v = cb + xs[i][p] * w0 + xs[i + 1][p] * w1 +
                  xs[i + 2][p] * w2 + xs[i + 3][p] * w3;
        float xdt = silu_mod(v) * dtbuf[i];
        y = y * ebuf[i] + gbuf[i] * xdt;
        outp[(size_t)i * 2048] = y;
    }
    Fb[((size_t)h * 64 + t) * 64 + p] = y;
    if (p == 0) Eb[(size_t)h * 64 + t] = expf(cum63);
}

// ---------------------------------------------------------------------------
// scanB: cross-chunk scan. 32 blocks x 64 threads.
// ---------------------------------------------------------------------------
__global__ __launch_bounds__(64) void scanB(
    const float* __restrict__ Fb, const float* __restrict__ Eb,
    float* __restrict__ Sprev)
{
    int idx = blockIdx.x * blockDim.x + threadIdx.x;  // 2048
    int p = idx & 63;
    int h = idx >> 6;
    int base = h * 64;
    float S = 0.f;
#pragma unroll 8
    for (int t = 0; t < 64; t++) {
        Sprev[(size_t)(base + t) * 64 + p] = S;
        S = S * Eb[base + t] + Fb[(size_t)(base + t) * 64 + p];
    }
}

// ---------------------------------------------------------------------------
// passC: y = (ylocal + S*decay) * silu_mod(z), emitted split bf16 directly in
// gemm2's A fragment-packed order (KCN=64).
// ---------------------------------------------------------------------------
__global__ __launch_bounds__(256) void passC(
    const float* __restrict__ yl, const float* __restrict__ z,
    const float* __restrict__ Sprev, const float* __restrict__ decay,
    unsigned short* __restrict__ yph, unsigned short* __restrict__ ypl)
{
    size_t idx = ((size_t)blockIdx.x * 256 + threadIdx.x) * 4;
    int row = (int)(idx >> 11);
    int cc = (int)(idx & 2047);
    int t = row >> 6;
    int h = cc >> 6, p = cc & 63;
    float4 av = *(const float4*)(yl + idx);
    float4 bvz = *(const float4*)(z + idx);
    float4 sv = *(const float4*)(Sprev + ((size_t)(h * 64 + t)) * 64 + p);
    float d = decay[(size_t)row * 32 + h];
    float4 yv;
    yv.x = (av.x + sv.x * d) * silu_mod(bvz.x);
    yv.y = (av.y + sv.y * d) * silu_mod(bvz.y);
    yv.z = (av.z + sv.z * d) * silu_mod(bvz.z);
    yv.w = (av.w + sv.w * d) * silu_mod(bvz.w);
    ushort4 hv, lv;
    split4(yv, &hv, &lv);
    size_t chunk = (((size_t)(row >> 4) * 64 + (cc >> 5)) * 64) + ((cc >> 3) & 3) * 16 + (row & 15);
    size_t o = chunk * 8 + (cc & 7);
    *(ushort4*)(yph + o) = hv;
    *(ushort4*)(ypl + o) = lv;
}

// ---------------------------------------------------------------------------
extern "C" void kernel_launch(void* const* d_in, const int* in_sizes, int n_in,
                              void* d_out, int out_size, void* d_ws, size_t ws_size,
                              hipStream_t stream)
{
    const float* u       = (const float*)d_in[0];
    const float* reward  = (const float*)d_in[1];
    const float* in_w    = (const float*)d_in[2];
    const float* in_b    = (const float*)d_in[3];
    const float* conv_w  = (const float*)d_in[4];
    const float* conv_b  = (const float*)d_in[5];
    const float* bw      = (const float*)d_in[6];
    const float* bb      = (const float*)d_in[7];
    const float* dt_bias = (const float*)d_in[8];
    const float* A_log   = (const float*)d_in[9];
    const float* out_w   = (const float*)d_in[10];
    float* out = (float*)d_out;

    char* p = (char*)d_ws;
    const size_t SEG = (size_t)4096 * 2048 * 4;  // 33,554,432 B
    float* z = (float*)p;                              // R0 (-> split-K partials)
    float* xc = (float*)(p + SEG);                     // R1 (-> ypacked)
    unsigned short* yph = (unsigned short*)(p + SEG);
    unsigned short* ypl = yph + (size_t)4096 * 2048;
    char* R2 = p + 2 * SEG;                            // R2
    float* ylocal = (float*)R2;
    char* ps = p + 3 * SEG;                            // tail
    float* dtraw = (float*)ps;                 ps += (size_t)4096 * 32 * 4;
    float* decay = (float*)ps;                 ps += (size_t)4096 * 32 * 4;
    float* Fb    = (float*)ps;                 ps += (size_t)32 * 64 * 64 * 4;
    float* Eb    = (float*)ps;                 ps += (size_t)32 * 64 * 4;
    float* Sprev = (float*)ps;                 ps += (size_t)32 * 64 * 64 * 4;

    const size_t W1PN = (size_t)264 * 32 * 64 * 8;  // shorts per w1 half
    const size_t W2PN = (size_t)64 * 64 * 64 * 8;   // shorts per w2 half
    const size_t UPN  = (size_t)256 * 32 * 64 * 8;  // shorts per u half
    const size_t DTWN = 32768;                      // floats, packed dt weights
    size_t used_small = (size_t)(ps - (char*)d_ws);
    bool wonce = ws_size >= used_small + 2 * sizeof(unsigned short) * (W1PN + W2PN);
    bool upack = ws_size >= used_small + 2 * sizeof(unsigned short) * (W1PN + W2PN + UPN)
                           + sizeof(float) * DTWN;

    unsigned short *w1ph, *w1pl, *w2ph, *w2pl, *uph = nullptr, *upl = nullptr;
    float* dtw = nullptr;
    if (wonce) {
        w1ph = (unsigned short*)ps;
        w1pl = w1ph + W1PN;
        w2ph = w1pl + W1PN;
        w2pl = w2ph + W2PN;
        pack_split<5, 1><<<2112, 256, 0, stream>>>(in_w, 1024, w1ph, w1pl);
        pack_split<6, 0><<<1024, 256, 0, stream>>>(out_w, 2048, w2ph, w2pl);
        if (upack) {
            uph = w2pl + W2PN;
            upl = uph + UPN;
            dtw = (float*)(upl + UPN);
            pack_dtw<<<128, 256, 0, stream>>>(in_w, dtw);
        }
    } else {
        w1ph = (unsigned short*)R2;
        w1pl = w1ph + W1PN;
        w2ph = (unsigned short*)R2;
        w2pl = w2ph + W2PN;
    }

    for (int b = 0; b < 4; b++) {
        const float* ub = u + (size_t)b * 4096 * 1024;
        const float* rb = reward + (size_t)b * 4096;
        float* ob = out + (size_t)b * 4096 * 1024;

        if (!wonce)
            pack_split<5, 1><<<2112, 256, 0, stream>>>(in_w, 1024, w1ph, w1pl);
        // 1) in_proj
        if (upack) {
            pack_split<5, 0><<<2048, 256, 0, stream>>>(ub, 1024, uph, upl);
            // main N=4096: 256 blocks = 1/CU, LDS-staged 256^2, 4-phase
            gemm256<32, 32, 0><<<256, 512, 0, stream>>>(
                uph, upl, w1ph, w1pl, in_b, z, xc,
                nullptr, nullptr, nullptr, nullptr);
            // dt columns (32): coalesced fp32 dot kernel
            dtproj2<<<512, 256, 0, stream>>>(ub, dtw, in_b, dtraw);
        } else {
            mfma_gemm<0, 0, 1024, 1, 0><<<1056, 256, 0, stream>>>(
                ub, nullptr, nullptr, w1ph, w1pl, in_b, z, xc, dtraw, nullptr);
        }
        // 2) conv + local chunk scan (xc -> ylocal in R2)
        scanA<<<2048, 64, 0, stream>>>(xc, dtraw, rb, conv_w, conv_b,
                                       dt_bias, A_log, bw, bb,
                                       ylocal, decay, Fb, Eb);
        // 3) cross-chunk scan
        scanB<<<32, 64, 0, stream>>>(Fb, Eb, Sprev);
        // 4) gate + carried state -> y fragment-packed into R1
        passC<<<8192, 256, 0, stream>>>(ylocal, z, Sprev, decay, yph, ypl);
        if (!wonce)
            pack_split<6, 0><<<1024, 256, 0, stream>>>(out_w, 2048, w2ph, w2pl);
        // 5) out_proj
        if (upack) {
            // split-K=4: 256 blocks; partials into dead z (R0) + ylocal (R2)
            float* pA = z;
            float* pB = z + (size_t)4096 * 1024;
            float* pC = ylocal;
            gemm256<64, 16, 1><<<256, 512, 0, stream>>>(
                yph, ypl, w2ph, w2pl, nullptr, nullptr, nullptr,
                ob, pA, pB, pC);
            addOut4<<<4096, 256, 0, stream>>>(ob, pA, pB, pC);
        } else {
            mfma_gemm<1, 1, 2048, 2, 0><<<512, 256, 0, stream>>>(
                nullptr, yph, ypl, w2ph, w2pl, nullptr,
                z, nullptr, nullptr, ob);
            addOut<<<4096, 256, 0, stream>>>(ob, z);
        }
    }
}

// Round 5
// 945.121 us; speedup vs baseline: 1.3400x; 1.1636x over previous
//
#include <hip/hip_runtime.h>
#include <hip/hip_bf16.h>
#include <math.h>

// D_MODEL=1024, D_INNER=2048, NHEADS=32, HEADDIM=64, CHUNK=64, B=4, L=4096
// C == ones collapses the state dim -> scalar scan per (h,p) channel.
//
// R5: in_proj main GEMM switched from bf16x3 (3 MFMA passes, 4 operand
// halves) to fp16x1 (1 pass): per K-tile/wave MFMA 96->32, LDS reads
// 24KB->12KB, LDS 128->64KB. fp16 RNE: ~2^-11 per product, ~0.035% rel on
// z/xc (u~N(0,1), w~0.02N in fp16 range). out_proj stays bf16x3.
// R2-R4 showed schedule variants all land at 94us -> byte-movement bound;
// this cuts bytes/pass count instead. u-f16 + w1-f16 reuse the old
// uph/upl workspace slots exactly (same footprint/tier condition).
//
// ws tiers (runtime-checked, deterministic):
//  small  ~100.3 MB : old layout, weights packed per batch, A split in-reg
//  +25.7  ~126.0 MB : weights packed once per call
//  +16.9  ~142.9 MB : f16 u/w1 packs -> gemm256h + dtproj2 path

typedef __attribute__((ext_vector_type(8))) short bf16x8;
typedef __attribute__((ext_vector_type(8))) _Float16 f16x8;
typedef __attribute__((ext_vector_type(4))) float f32x4;

__device__ __forceinline__ float bf2f(unsigned short u) {
    union { float f; unsigned int i; } x; x.i = ((unsigned int)u) << 16; return x.f;
}
__device__ __forceinline__ unsigned short f2bf(float f) {  // RNE
    union { float f; unsigned int i; } x; x.f = f;
    unsigned int r = x.i + 0x7fffu + ((x.i >> 16) & 1u);
    return (unsigned short)(r >> 16);
}
__device__ __forceinline__ unsigned short f2h(float f) {   // fp16 RNE bits
    _Float16 h = (_Float16)f;
    unsigned short u; __builtin_memcpy(&u, &h, 2); return u;
}
__device__ __forceinline__ float softplusf(float x) {
    return (x > 20.f) ? x : log1pf(expf(x));
}
__device__ __forceinline__ float silu_mod(float x) {  // sigmoid(x)+0.1x per ref
    return 1.f / (1.f + expf(-x)) + 0.1f * x;
}
__device__ __forceinline__ void cvt_split2(float x, float y,
                                           unsigned int* hi, unsigned int* lo) {
    __hip_bfloat162 h2 = __float22bfloat162_rn(make_float2(x, y));
    unsigned int h; __builtin_memcpy(&h, &h2, 4);
    union { float f; unsigned int i; } fx, fy;
    fx.i = h << 16;
    fy.i = h & 0xffff0000u;
    __hip_bfloat162 l2 = __float22bfloat162_rn(make_float2(x - fx.f, y - fy.f));
    unsigned int l; __builtin_memcpy(&l, &l2, 4);
    *hi = h; *lo = l;
}
__device__ __forceinline__ void split4(float4 v, ushort4* h, ushort4* l) {
    unsigned short t;
    t = f2bf(v.x); h->x = t; l->x = f2bf(v.x - bf2f(t));
    t = f2bf(v.y); h->y = t; l->y = f2bf(v.y - bf2f(t));
    t = f2bf(v.z); h->z = t; l->z = f2bf(v.z - bf2f(t));
    t = f2bf(v.w); h->w = t; l->w = f2bf(v.w - bf2f(t));
}

// ---------------------------------------------------------------------------
// pack row-major fp32 -> fragment-order split bf16.
// thread t -> (tile = t>>(6+KCN_LOG), kc = (t>>6)&(KCN-1), lane = t&63):
//   data = src[tile*16 + (lane&15)][kc*32 + (lane>>4)*8 .. +8]
// REMAP (in_w): row<4096 -> row; 4096..4127 -> row+128 (dt cols); else zero.
// ---------------------------------------------------------------------------
template <int KCN_LOG, int REMAP>
__global__ __launch_bounds__(256) void pack_split(
    const float* __restrict__ src, int src_ld,
    unsigned short* __restrict__ h, unsigned short* __restrict__ l)
{
    int t = blockIdx.x * 256 + threadIdx.x;
    int lane = t & 63;
    int kc = (t >> 6) & ((1 << KCN_LOG) - 1);
    int tile = t >> (6 + KCN_LOG);
    int n = tile * 16 + (lane & 15);
    int k = kc * 32 + (lane >> 4) * 8;
    int sr = n;
    if (REMAP) sr = (n < 4096) ? n : (n < 4128 ? n + 128 : -1);
    float4 v0 = make_float4(0.f, 0.f, 0.f, 0.f), v1 = v0;
    if (sr >= 0) {
        const float* s = src + (size_t)sr * src_ld + k;
        v0 = *(const float4*)s;
        v1 = *(const float4*)(s + 4);
    }
    ushort4 h0, l0, h1, l1;
    split4(v0, &h0, &l0);
    split4(v1, &h1, &l1);
    size_t o = (size_t)t * 8;
    *(ushort4*)(h + o) = h0; *(ushort4*)(h + o + 4) = h1;
    *(ushort4*)(l + o) = l0; *(ushort4*)(l + o + 4) = l1;
}

// ---------------------------------------------------------------------------
// pack_f16: row-major fp32 -> fragment-order fp16 (single copy). Same
// thread->element mapping as pack_split. src_ld = KCN*32.
// ---------------------------------------------------------------------------
template <int KCN_LOG>
__global__ __launch_bounds__(256) void pack_f16(
    const float* __restrict__ src, unsigned short* __restrict__ d)
{
    int t = blockIdx.x * 256 + threadIdx.x;
    int lane = t & 63;
    int kc = (t >> 6) & ((1 << KCN_LOG) - 1);
    int tile = t >> (6 + KCN_LOG);
    int n = tile * 16 + (lane & 15);
    int k = kc * 32 + (lane >> 4) * 8;
    const float* s = src + (size_t)n * (32 << KCN_LOG) + k;
    float4 v0 = *(const float4*)s;
    float4 v1 = *(const float4*)(s + 4);
    ushort4 h0, h1;
    h0.x = f2h(v0.x); h0.y = f2h(v0.y); h0.z = f2h(v0.z); h0.w = f2h(v0.w);
    h1.x = f2h(v1.x); h1.y = f2h(v1.y); h1.z = f2h(v1.z); h1.w = f2h(v1.w);
    size_t o = (size_t)t * 8;
    *(ushort4*)(d + o) = h0; *(ushort4*)(d + o + 4) = h1;
}

// ---------------------------------------------------------------------------
// pack_dtw: dt weight rows 4224..4255 of in_w -> dtw[k4][h][4] fp32 (128 KB),
// so dtproj2's 32-lane h-groups read contiguous 512B. Once per call.
// ---------------------------------------------------------------------------
__global__ __launch_bounds__(256) void pack_dtw(
    const float* __restrict__ in_w, float* __restrict__ dtw)
{
    int o = blockIdx.x * 256 + threadIdx.x;   // 32768
    int k4 = o >> 7, rem = o & 127;
    int h = rem >> 2, r = rem & 3;
    dtw[o] = in_w[(size_t)(4224 + h) * 1024 + k4 * 4 + r];
}

// ---------------------------------------------------------------------------
// dtproj2: dtraw[l,h] = dot(u[l,:], dt_w[h,:]) + in_b[4224+h], fp32.
// ---------------------------------------------------------------------------
__global__ __launch_bounds__(256) void dtproj2(
    const float* __restrict__ u, const float* __restrict__ dtw,
    const float* __restrict__ in_b, float* __restrict__ dtraw)
{
    int idx = blockIdx.x * 256 + threadIdx.x;
    int l = idx >> 5, h = idx & 31;
    const float* ur = u + (size_t)l * 1024;
    const float* wp = dtw + h * 4;
    float s0 = 0.f, s1 = 0.f, s2 = 0.f, s3 = 0.f;
#pragma unroll 4
    for (int k4 = 0; k4 < 256; k4++) {
        float4 a = *(const float4*)(ur + k4 * 4);
        float4 b = *(const float4*)(wp + (size_t)k4 * 128);
        s0 += a.x * b.x; s1 += a.y * b.y;
        s2 += a.z * b.z; s3 += a.w * b.w;
    }
    dtraw[idx] = (s0 + s1) + (s2 + s3) + in_b[4224 + h];
}

// ---------------------------------------------------------------------------
// LDS-free bf16x3 MFMA NT-GEMM (old structure) — kept for fallback tiers.
// ---------------------------------------------------------------------------
template <int ASRC, int OUT, int KDIM, int KSPLIT, int NOFF>
__global__ __launch_bounds__(256, 2) void mfma_gemm(
    const float* __restrict__ Af,
    const unsigned short* __restrict__ Aph, const unsigned short* __restrict__ Apl,
    const unsigned short* __restrict__ Bph, const unsigned short* __restrict__ Bpl,
    const float* __restrict__ bias,
    float* __restrict__ oz, float* __restrict__ oxc,
    float* __restrict__ dtraw, float* __restrict__ outC)
{
    constexpr int KCN = KDIM / 32;       // layout stride (total K chunks)
    constexpr int KCNL = KCN / KSPLIT;   // chunks this block iterates
    const int g = blockIdx.x;
    const int ks = (KSPLIT > 1) ? (g >> 8) : 0;
    const int gg = (KSPLIT > 1) ? (g & 255) : g;
    const int m0 = ((gg & 7) * 4 + ((gg >> 3) & 3)) * 128;
    const int n0 = (gg >> 5) * 128 + NOFF;
    const int tid = threadIdx.x;
    const int lane = tid & 63, w = tid >> 6;
    const int wm = w & 1, wn = w >> 1;
    const int fr = lane & 15, q = lane >> 4;
    const size_t koff = (size_t)ks * KCNL * 512;  // shorts

    const unsigned short* bhp[4];
    const unsigned short* blp[4];
#pragma unroll
    for (int nt = 0; nt < 4; nt++) {
        size_t c = ((size_t)((n0 >> 4) + wn * 4 + nt) * KCN * 64 + lane) * 8 + koff;
        bhp[nt] = Bph + c;
        blp[nt] = Bpl + c;
    }
    const float* afp[4];
    const unsigned short* ahp[4];
    const unsigned short* alp[4];
#pragma unroll
    for (int mt = 0; mt < 4; mt++) {
        if (ASRC == 0) {
            afp[mt] = Af + (size_t)(m0 + wm * 64 + mt * 16 + fr) * KDIM + q * 8
                         + (size_t)ks * (KDIM / KSPLIT);
        } else {
            size_t c = ((size_t)((m0 >> 4) + wm * 4 + mt) * KCN * 64 + lane) * 8 + koff;
            ahp[mt] = Aph + c;
            alp[mt] = Apl + c;
        }
    }

    f32x4 acc[4][4];
#pragma unroll
    for (int i = 0; i < 4; i++)
#pragma unroll
        for (int j = 0; j < 4; j++) acc[i][j] = (f32x4){0.f, 0.f, 0.f, 0.f};

    bf16x8 bh[2][4], bl[2][4], ah[2][4], al[2][4];
    float4 af0[2][4], af1[2][4];

#define LOAD_STEP(B)                                                          \
    {                                                                         \
        _Pragma("unroll") for (int nt = 0; nt < 4; nt++) {                    \
            bh[B][nt] = *(const bf16x8*)bhp[nt];                              \
            bl[B][nt] = *(const bf16x8*)blp[nt];                              \
            bhp[nt] += 512; blp[nt] += 512;                                   \
        }                                                                     \
        _Pragma("unroll") for (int mt = 0; mt < 4; mt++) {                    \
            if (ASRC == 1) {                                                  \
                ah[B][mt] = *(const bf16x8*)ahp[mt];                          \
                al[B][mt] = *(const bf16x8*)alp[mt];                          \
                ahp[mt] += 512; alp[mt] += 512;                               \
            } else {                                                          \
                af0[B][mt] = *(const float4*)afp[mt];                         \
                af1[B][mt] = *(const float4*)(afp[mt] + 4);                   \
                afp[mt] += 32;                                                \
            }                                                                 \
        }                                                                     \
    }

#define MFMA_STEP(B)                                                          \
    {                                                                         \
        bf16x8 xah[4], xal[4];                                                \
        _Pragma("unroll") for (int mt = 0; mt < 4; mt++) {                    \
            if (ASRC == 1) {                                                  \
                xah[mt] = ah[B][mt]; xal[mt] = al[B][mt];                     \
            } else {                                                          \
                union { bf16x8 v; unsigned int u[4]; } H, L;                  \
                cvt_split2(af0[B][mt].x, af0[B][mt].y, &H.u[0], &L.u[0]);     \
                cvt_split2(af0[B][mt].z, af0[B][mt].w, &H.u[1], &L.u[1]);     \
                cvt_split2(af1[B][mt].x, af1[B][mt].y, &H.u[2], &L.u[2]);     \
                cvt_split2(af1[B][mt].z, af1[B][mt].w, &H.u[3], &L.u[3]);     \
                xah[mt] = H.v; xal[mt] = L.v;                                 \
            }                                                                 \
        }                                                                     \
        _Pragma("unroll") for (int mt = 0; mt < 4; mt++)                      \
            _Pragma("unroll") for (int nt = 0; nt < 4; nt++)                  \
                acc[mt][nt] = __builtin_amdgcn_mfma_f32_16x16x32_bf16(        \
                    xah[mt], bh[B][nt], acc[mt][nt], 0, 0, 0);                \
        _Pragma("unroll") for (int mt = 0; mt < 4; mt++)                      \
            _Pragma("unroll") for (int nt = 0; nt < 4; nt++)                  \
                acc[mt][nt] = __builtin_amdgcn_mfma_f32_16x16x32_bf16(        \
                    xah[mt], bl[B][nt], acc[mt][nt], 0, 0, 0);                \
        _Pragma("unroll") for (int mt = 0; mt < 4; mt++)                      \
            _Pragma("unroll") for (int nt = 0; nt < 4; nt++)                  \
                acc[mt][nt] = __builtin_amdgcn_mfma_f32_16x16x32_bf16(        \
                    xal[mt], bh[B][nt], acc[mt][nt], 0, 0, 0);                \
    }

    LOAD_STEP(0);
    for (int kc = 0; kc + 2 < KCNL; kc += 2) {
        LOAD_STEP(1);
        MFMA_STEP(0);
        LOAD_STEP(0);
        MFMA_STEP(1);
    }
    LOAD_STEP(1);
    MFMA_STEP(0);
    MFMA_STEP(1);
#undef LOAD_STEP
#undef MFMA_STEP

    // epilogue: D[row=q*4+reg][col=fr] per 16x16 tile
#pragma unroll
    for (int nt = 0; nt < 4; nt++) {
        int jn = n0 + wn * 64 + nt * 16 + fr;
        if (OUT == 0 && jn >= 4128) continue;
        float bv = 0.f;
        if (OUT == 0) bv = bias[jn < 4096 ? jn : jn + 128];
#pragma unroll
        for (int mt = 0; mt < 4; mt++) {
#pragma unroll
            for (int reg = 0; reg < 4; reg++) {
                int rm = m0 + wm * 64 + mt * 16 + q * 4 + reg;
                float v = acc[mt][nt][reg] + bv;
                if (OUT == 0) {
                    if (jn < 2048)      oz[(size_t)rm * 2048 + jn] = v;
                    else if (jn < 4096) oxc[(size_t)rm * 2048 + (jn - 2048)] = v;
                    else                dtraw[(size_t)rm * 32 + (jn - 4096)] = v;
                } else {
                    float* dst = (KSPLIT == 1 || ks == 0) ? outC : oz;
                    dst[(size_t)rm * 1024 + jn] = v;
                }
            }
        }
    }
}

// ---------------------------------------------------------------------------
// gemm256h: fp16 single-pass 256x256 GEMM for in_proj main (N=4096).
// 512 threads (8 waves, 2M x 4N), BK=32. LDS 64KB: 2 buf x (A 16KB + B 16KB)
// fragment order (ds_read_b128 stride-1: conflict-free). Per K-tile/wave:
// 4 gload_lds stage(k+1), 12 ds_read, 32 MFMA. Simple 2-barrier loop
// (R2-R4 showed schedule variants equivalent at this regime).
// ---------------------------------------------------------------------------
template <int KCN, int NT>
__global__ __launch_bounds__(512, 2) void gemm256h(
    const unsigned short* __restrict__ Ap, const unsigned short* __restrict__ Bp,
    const float* __restrict__ bias,
    float* __restrict__ oz, float* __restrict__ oxc)
{
    __shared__ unsigned short smem[32768];  // 64 KiB
    const int g = blockIdx.x;
    const int xcd = g & 7, loc = g >> 3;     // XCD x owns n-blocks {2x,2x+1}
    const int nb = xcd * 2 + (loc & 1);
    const int mb = loc >> 1;
    const int tid = threadIdx.x;
    const int lane = tid & 63, w = tid >> 6;
    const int wm = w & 1, wn = w >> 1;
    const int fr = lane & 15, q = lane >> 4;

    // per-wave staging: A tiles {2w,2w+1}, B tiles {2w,2w+1} (4 gload_lds)
    const unsigned short* gp[4];
    {
        const int tA0 = mb * 16 + 2 * w;
        const int tB0 = nb * 16 + 2 * w;
        gp[0] = Ap + ((size_t)tA0 * KCN) * 512 + lane * 8;
        gp[1] = Ap + ((size_t)(tA0 + 1) * KCN) * 512 + lane * 8;
        gp[2] = Bp + ((size_t)tB0 * KCN) * 512 + lane * 8;
        gp[3] = Bp + ((size_t)(tB0 + 1) * KCN) * 512 + lane * 8;
    }
    int ldso[4];
    {
        const int t0 = 2 * w * 512, t1 = t0 + 512;
        ldso[0] = t0;         ldso[1] = t1;          // A
        ldso[2] = 8192 + t0;  ldso[3] = 8192 + t1;   // B
    }

#define STAGE(BUF)                                                            \
    {                                                                         \
        unsigned short* bp = smem + (BUF) * 16384;                            \
        _Pragma("unroll") for (int i = 0; i < 4; i++) {                       \
            __builtin_amdgcn_global_load_lds(                                 \
                (const __attribute__((address_space(1))) unsigned int*)gp[i], \
                (__attribute__((address_space(3))) unsigned int*)(bp + ldso[i]), \
                16, 0, 0);                                                    \
            gp[i] += 512;                                                     \
        }                                                                     \
    }

    f32x4 acc[8][4];
#pragma unroll
    for (int i = 0; i < 8; i++)
#pragma unroll
        for (int j = 0; j < 4; j++) acc[i][j] = (f32x4){0.f, 0.f, 0.f, 0.f};

    STAGE(0);
    __syncthreads();
    for (int kt = 0; kt < NT; ++kt) {
        const int cur = kt & 1;
        if (kt + 1 < NT) STAGE(cur ^ 1);
        const unsigned short* sb = smem + cur * 16384;
        f16x8 Bv[4];
#pragma unroll
        for (int nt = 0; nt < 4; nt++)
            Bv[nt] = *(const f16x8*)(sb + 8192 + (wn * 4 + nt) * 512 + lane * 8);
#pragma unroll
        for (int mt = 0; mt < 8; mt++) {
            f16x8 av = *(const f16x8*)(sb + (wm * 8 + mt) * 512 + lane * 8);
            __builtin_amdgcn_s_setprio(1);
#pragma unroll
            for (int nt = 0; nt < 4; nt++)
                acc[mt][nt] = __builtin_amdgcn_mfma_f32_16x16x32_f16(
                    av, Bv[nt], acc[mt][nt], 0, 0, 0);
            __builtin_amdgcn_s_setprio(0);
        }
        __syncthreads();
    }
#undef STAGE

    // epilogue: D[row=q*4+reg][col=fr] per 16x16 tile
    const int m0 = mb * 256, n0 = nb * 256;
#pragma unroll
    for (int nt = 0; nt < 4; nt++) {
        const int jn = n0 + wn * 64 + nt * 16 + fr;
        const float bv = bias[jn];
#pragma unroll
        for (int mt = 0; mt < 8; mt++) {
#pragma unroll
            for (int reg = 0; reg < 4; reg++) {
                const int rm = m0 + wm * 128 + mt * 16 + q * 4 + reg;
                float v = acc[mt][nt][reg] + bv;
                if (jn < 2048) oz[(size_t)rm * 2048 + jn] = v;
                else           oxc[(size_t)rm * 2048 + (jn - 2048)] = v;
            }
        }
    }
}

// ---------------------------------------------------------------------------
// gemm256: bf16x3 256x256 LDS-staged GEMM, 4-phase K-tile (R4) — out_proj
// split-K=4 path. OUT 0 retained for completeness.
// ---------------------------------------------------------------------------
template <int KCN, int NT, int OUT>
__global__ __launch_bounds__(512, 2) void gemm256(
    const unsigned short* __restrict__ Aph, const unsigned short* __restrict__ Apl,
    const unsigned short* __restrict__ Bph, const unsigned short* __restrict__ Bpl,
    const float* __restrict__ bias,
    float* __restrict__ oz, float* __restrict__ oxc,
    float* __restrict__ outC,
    float* __restrict__ p1, float* __restrict__ p2, float* __restrict__ p3)
{
    __shared__ unsigned short smem[65536];  // 128 KiB
    const int g = blockIdx.x;
    int mb, nb, kt0;
    float* dst = outC;
    if (OUT == 0) {
        const int xcd = g & 7, loc = g >> 3;
        nb = xcd * 2 + (loc & 1);
        mb = loc >> 1;
        kt0 = 0;
    } else {
        const int ks = g >> 6, loc = g & 63;
        mb = loc & 15; nb = loc >> 4; kt0 = ks * NT;
        dst = (ks == 0) ? outC : (ks == 1 ? p1 : (ks == 2 ? p2 : p3));
    }
    const int tid = threadIdx.x;
    const int lane = tid & 63, w = tid >> 6;
    const int wm = w & 1, wn = w >> 1;
    const int fr = lane & 15, q = lane >> 4;

    const unsigned short* gp[8];
    {
        const int tA0 = mb * 16 + 2 * w;
        const int tB0 = nb * 16 + 2 * w;
        size_t a0 = ((size_t)tA0 * KCN + kt0) * 512 + lane * 8;
        size_t a1 = ((size_t)(tA0 + 1) * KCN + kt0) * 512 + lane * 8;
        size_t b0 = ((size_t)tB0 * KCN + kt0) * 512 + lane * 8;
        size_t b1 = ((size_t)(tB0 + 1) * KCN + kt0) * 512 + lane * 8;
        gp[0] = Aph + a0; gp[1] = Aph + a1;
        gp[2] = Apl + a0; gp[3] = Apl + a1;
        gp[4] = Bph + b0; gp[5] = Bph + b1;
        gp[6] = Bpl + b0; gp[7] = Bpl + b1;
    }
    int ldso[8];
    {
        const int t0 = 2 * w * 512, t1 = t0 + 512;
        ldso[0] = t0;          ldso[1] = t1;          // Ah
        ldso[2] = 8192 + t0;   ldso[3] = 8192 + t1;   // Al
        ldso[4] = 16384 + t0;  ldso[5] = 16384 + t1;  // Bh
        ldso[6] = 24576 + t0;  ldso[7] = 24576 + t1;  // Bl
    }

#define ISSUE(i, bp)                                                          \
    __builtin_amdgcn_global_load_lds(                                         \
        (const __attribute__((address_space(1))) unsigned int*)gp[i],         \
        (__attribute__((address_space(3))) unsigned int*)((bp) + ldso[i]),    \
        16, 0, 0);                                                            \
    gp[i] += 512;

#define CFENCE asm volatile("" ::: "memory")

#define MFMA1(av, bv, MT, NTI)                                                \
    acc[MT][NTI] = __builtin_amdgcn_mfma_f32_16x16x32_bf16(                   \
        av, bv, acc[MT][NTI], 0, 0, 0)

#define CLUSTER24(MT0, MT1, A0H, A1H, A0L, A1L)                               \
    __builtin_amdgcn_s_setprio(1);                                            \
    _Pragma("unroll") for (int nt = 0; nt < 4; nt++)                          \
        MFMA1(A0H, Bh_[nt], MT0, nt);                                         \
    _Pragma("unroll") for (int nt = 0; nt < 4; nt++)                          \
        MFMA1(A1H, Bh_[nt], MT1, nt);                                         \
    _Pragma("unroll") for (int nt = 0; nt < 4; nt++)                          \
        MFMA1(A0H, Bl_[nt], MT0, nt);                                         \
    _Pragma("unroll") for (int nt = 0; nt < 4; nt++)                          \
        MFMA1(A1H, Bl_[nt], MT1, nt);                                         \
    _Pragma("unroll") for (int nt = 0; nt < 4; nt++)                          \
        MFMA1(A0L, Bh_[nt], MT0, nt);                                         \
    _Pragma("unroll") for (int nt = 0; nt < 4; nt++)                          \
        MFMA1(A1L, Bh_[nt], MT1, nt);                                         \
    __builtin_amdgcn_s_setprio(0);

#define PHASE_TAIL(GI0, GI1, MT0, MT1)                                        \
    {                                                                         \
        if (pre) { ISSUE(GI0, bpn) ISSUE(GI1, bpn) }                          \
        bf16x8 a0h = *(const bf16x8*)(sb + (wm * 8 + MT0) * 512 + lane * 8);  \
        bf16x8 a1h = *(const bf16x8*)(sb + (wm * 8 + MT1) * 512 + lane * 8);  \
        bf16x8 a0l = *(const bf16x8*)(sb + 8192 + (wm * 8 + MT0) * 512 + lane * 8); \
        bf16x8 a1l = *(const bf16x8*)(sb + 8192 + (wm * 8 + MT1) * 512 + lane * 8); \
        __builtin_amdgcn_s_barrier(); CFENCE;                                 \
        asm volatile("s_waitcnt lgkmcnt(0)" ::: "memory");                    \
        __builtin_amdgcn_sched_barrier(0);                                    \
        CLUSTER24(MT0, MT1, a0h, a1h, a0l, a1l)                               \
        __builtin_amdgcn_s_barrier(); CFENCE;                                 \
    }

    f32x4 acc[8][4];
#pragma unroll
    for (int i = 0; i < 8; i++)
#pragma unroll
        for (int j = 0; j < 4; j++) acc[i][j] = (f32x4){0.f, 0.f, 0.f, 0.f};

    {
        unsigned short* bp = smem;
        ISSUE(0, bp) ISSUE(1, bp) ISSUE(2, bp) ISSUE(3, bp)
        ISSUE(4, bp) ISSUE(5, bp) ISSUE(6, bp) ISSUE(7, bp)
    }
    asm volatile("s_waitcnt vmcnt(0)" ::: "memory");
    __builtin_amdgcn_s_barrier();
    CFENCE;

    bf16x8 Bh_[4], Bl_[4];

    for (int kt = 0; kt < NT; ++kt) {
        const int cur = kt & 1;
        const unsigned short* sb = smem + cur * 32768;
        unsigned short* bpn = smem + (cur ^ 1) * 32768;
        const bool pre = (kt + 1 < NT);

        if (pre) {
            ISSUE(4, bpn) ISSUE(5, bpn)
            asm volatile("s_waitcnt vmcnt(2)" ::: "memory");
        } else {
            asm volatile("s_waitcnt vmcnt(0)" ::: "memory");
        }
        __builtin_amdgcn_s_barrier(); CFENCE;
        {
#pragma unroll
            for (int nt = 0; nt < 4; nt++) {
                Bh_[nt] = *(const bf16x8*)(sb + 16384 + (wn * 4 + nt) * 512 + lane * 8);
                Bl_[nt] = *(const bf16x8*)(sb + 24576 + (wn * 4 + nt) * 512 + lane * 8);
            }
            bf16x8 a0h = *(const bf16x8*)(sb + (wm * 8 + 0) * 512 + lane * 8);
            bf16x8 a1h = *(const bf16x8*)(sb + (wm * 8 + 1) * 512 + lane * 8);
            bf16x8 a0l = *(const bf16x8*)(sb + 8192 + (wm * 8 + 0) * 512 + lane * 8);
            bf16x8 a1l = *(const bf16x8*)(sb + 8192 + (wm * 8 + 1) * 512 + lane * 8);
            asm volatile("s_waitcnt lgkmcnt(0)" ::: "memory");
            __builtin_amdgcn_sched_barrier(0);
            CLUSTER24(0, 1, a0h, a1h, a0l, a1l)
        }
        __builtin_amdgcn_s_barrier(); CFENCE;

        PHASE_TAIL(6, 7, 2, 3)
        PHASE_TAIL(0, 1, 4, 5)
        PHASE_TAIL(2, 3, 6, 7)
    }
#undef ISSUE
#undef CFENCE
#undef MFMA1
#undef CLUSTER24
#undef PHASE_TAIL

    const int m0 = mb * 256, n0 = nb * 256;
#pragma unroll
    for (int nt = 0; nt < 4; nt++) {
        const int jn = n0 + wn * 64 + nt * 16 + fr;
        float bv = 0.f;
        if (OUT == 0) bv = bias[jn];
#pragma unroll
        for (int mt = 0; mt < 8; mt++) {
#pragma unroll
            for (int reg = 0; reg < 4; reg++) {
                const int rm = m0 + wm * 128 + mt * 16 + q * 4 + reg;
                float v = acc[mt][nt][reg] + bv;
                if (OUT == 0) {
                    if (jn < 2048) oz[(size_t)rm * 2048 + jn] = v;
                    else           oxc[(size_t)rm * 2048 + (jn - 2048)] = v;
                } else {
                    dst[(size_t)rm * 1024 + jn] = v;
                }
            }
        }
    }
}

// ---------------------------------------------------------------------------
// split-K reductions.
// ---------------------------------------------------------------------------
__global__ __launch_bounds__(256) void addOut(
    float* __restrict__ dst, const float* __restrict__ part)
{
    size_t i = ((size_t)blockIdx.x * 256 + threadIdx.x) * 4;
    float4 a = *(const float4*)(dst + i);
    float4 b = *(const float4*)(part + i);
    a.x += b.x; a.y += b.y; a.z += b.z; a.w += b.w;
    *(float4*)(dst + i) = a;
}

__global__ __launch_bounds__(256) void addOut4(
    float* __restrict__ dst, const float* __restrict__ a,
    const float* __restrict__ b, const float* __restrict__ c)
{
    size_t i = ((size_t)blockIdx.x * 256 + threadIdx.x) * 4;
    float4 d = *(const float4*)(dst + i);
    float4 x = *(const float4*)(a + i);
    float4 y = *(const float4*)(b + i);
    float4 zz = *(const float4*)(c + i);
    d.x += x.x + y.x + zz.x;
    d.y += x.y + y.y + zz.y;
    d.z += x.z + y.z + zz.z;
    d.w += x.w + y.w + zz.w;
    *(float4*)(dst + i) = d;
}

// ---------------------------------------------------------------------------
// scanA: one batch. Per (h, chunk) block, 64 threads (p). conv4 + silu' +
// softplus(dt) + decay cumsum + 64-step local scan. xc/ylocal fp32.
// ---------------------------------------------------------------------------
__global__ __launch_bounds__(64) void scanA(
    const float* __restrict__ xc,
    const float* __restrict__ dtraw, const float* __restrict__ reward,
    const float* __restrict__ conv_w, const float* __restrict__ conv_b,
    const float* __restrict__ dt_bias, const float* __restrict__ A_log,
    const float* __restrict__ bw, const float* __restrict__ bb,
    float* __restrict__ ylocal,
    float* __restrict__ decay, float* __restrict__ Fb, float* __restrict__ Eb)
{
    const int blk = blockIdx.x;        // h*64 + t
    const int t = blk & 63;
    const int h = blk >> 6;
    const int p = threadIdx.x;
    const int l0 = t * 64;

    __shared__ float xs[67][65];
    __shared__ float gbuf[64], ebuf[64], dtbuf[64];
    __shared__ float cum63;

    float v1 = bw[p] + bw[p + 64];
    float v2 = bb[p] + bb[p + 64];
#pragma unroll
    for (int o = 32; o > 0; o >>= 1) {
        v1 += __shfl_down(v1, o, 64);
        v2 += __shfl_down(v2, o, 64);
    }
    const float sbw = __shfl(v1, 0, 64);
    const float sbb = __shfl(v2, 0, 64);

    const int l = l0 + p;
    const float dt = softplusf(dtraw[(size_t)l * 32 + h] + dt_bias[h]);
    const float a = -expf(A_log[h]) * dt;
    float cum = a;
#pragma unroll
    for (int o = 1; o < 64; o <<= 1) {
        float uo = __shfl_up(cum, o, 64);
        if (p >= o) cum += uo;
    }
    decay[(size_t)l * 32 + h] = expf(cum);
    gbuf[p] = reward[l] * sbw + sbb;
    ebuf[p] = expf(a);
    dtbuf[p] = dt;
    if (p == 63) cum63 = cum;

    const int c = h * 64 + p;
    for (int r = 0; r < 67; r++) {
        int ls = l0 - 3 + r;
        xs[r][p] = (ls >= 0) ? xc[(size_t)ls * 2048 + c] : 0.f;
    }
    __syncthreads();

    const float w0 = conv_w[c * 4 + 0], w1 = conv_w[c * 4 + 1],
                w2 = conv_w[c * 4 + 2], w3 = conv_w[c * 4 + 3];
    const float cb = conv_b[c];
    float y = 0.f;
    float* outp = ylocal + (size_t)l0 * 2048 + c;
#pragma unroll 4
    for (int i = 0; i < 64; i++) {
        float v = cb + xs[i][p] * w0 + xs[i + 1][p] * w1 +
                  xs[i + 2][p] * w2 + xs[i + 3][p] * w3;
        float xdt = silu_mod(v) * dtbuf[i];
        y = y * ebuf[i] + gbuf[i] * xdt;
        outp[(size_t)i * 2048] = y;
    }
    Fb[((size_t)h * 64 + t) * 64 + p] = y;
    if (p == 0) Eb[(size_t)h * 64 + t] = expf(cum63);
}

// ---------------------------------------------------------------------------
// scanB: cross-chunk scan. 32 blocks x 64 threads.
// ---------------------------------------------------------------------------
__global__ __launch_bounds__(64) void scanB(
    const float* __restrict__ Fb, const float* __restrict__ Eb,
    float* __restrict__ Sprev)
{
    int idx = blockIdx.x * blockDim.x + threadIdx.x;  // 2048
    int p = idx & 63;
    int h = idx >> 6;
    int base = h * 64;
    float S = 0.f;
#pragma unroll 8
    for (int t = 0; t < 64; t++) {
        Sprev[(size_t)(base + t) * 64 + p] = S;
        S = S * Eb[base + t] + Fb[(size_t)(base + t) * 64 + p];
    }
}

// ---------------------------------------------------------------------------
// passC: y = (ylocal + S*decay) * silu_mod(z), emitted split bf16 directly in
// gemm2's A fragment-packed order (KCN=64).
// ---------------------------------------------------------------------------
__global__ __launch_bounds__(256) void passC(
    const float* __restrict__ yl, const float* __restrict__ z,
    const float* __restrict__ Sprev, const float* __restrict__ decay,
    unsigned short* __restrict__ yph, unsigned short* __restrict__ ypl)
{
    size_t idx = ((size_t)blockIdx.x * 256 + threadIdx.x) * 4;
    int row = (int)(idx >> 11);
    int cc = (int)(idx & 2047);
    int t = row >> 6;
    int h = cc >> 6, p = cc & 63;
    float4 av = *(const float4*)(yl + idx);
    float4 bvz = *(const float4*)(z + idx);
    float4 sv = *(const float4*)(Sprev + ((size_t)(h * 64 + t)) * 64 + p);
    float d = decay[(size_t)row * 32 + h];
    float4 yv;
    yv.x = (av.x + sv.x * d) * silu_mod(bvz.x);
    yv.y = (av.y + sv.y * d) * silu_mod(bvz.y);
    yv.z = (av.z + sv.z * d) * silu_mod(bvz.z);
    yv.w = (av.w + sv.w * d) * silu_mod(bvz.w);
    ushort4 hv, lv;
    split4(yv, &hv, &lv);
    size_t chunk = (((size_t)(row >> 4) * 64 + (cc >> 5)) * 64) + ((cc >> 3) & 3) * 16 + (row & 15);
    size_t o = chunk * 8 + (cc & 7);
    *(ushort4*)(yph + o) = hv;
    *(ushort4*)(ypl + o) = lv;
}

// ---------------------------------------------------------------------------
extern "C" void kernel_launch(void* const* d_in, const int* in_sizes, int n_in,
                              void* d_out, int out_size, void* d_ws, size_t ws_size,
                              hipStream_t stream)
{
    const float* u       = (const float*)d_in[0];
    const float* reward  = (const float*)d_in[1];
    const float* in_w    = (const float*)d_in[2];
    const float* in_b    = (const float*)d_in[3];
    const float* conv_w  = (const float*)d_in[4];
    const float* conv_b  = (const float*)d_in[5];
    const float* bw      = (const float*)d_in[6];
    const float* bb      = (const float*)d_in[7];
    const float* dt_bias = (const float*)d_in[8];
    const float* A_log   = (const float*)d_in[9];
    const float* out_w   = (const float*)d_in[10];
    float* out = (float*)d_out;

    char* p = (char*)d_ws;
    const size_t SEG = (size_t)4096 * 2048 * 4;  // 33,554,432 B
    float* z = (float*)p;                              // R0 (-> split-K partials)
    float* xc = (float*)(p + SEG);                     // R1 (-> ypacked)
    unsigned short* yph = (unsigned short*)(p + SEG);
    unsigned short* ypl = yph + (size_t)4096 * 2048;
    char* R2 = p + 2 * SEG;                            // R2
    float* ylocal = (float*)R2;
    char* ps = p + 3 * SEG;                            // tail
    float* dtraw = (float*)ps;                 ps += (size_t)4096 * 32 * 4;
    float* decay = (float*)ps;                 ps += (size_t)4096 * 32 * 4;
    float* Fb    = (float*)ps;                 ps += (size_t)32 * 64 * 64 * 4;
    float* Eb    = (float*)ps;                 ps += (size_t)32 * 64 * 4;
    float* Sprev = (float*)ps;                 ps += (size_t)32 * 64 * 64 * 4;

    const size_t W1PN = (size_t)264 * 32 * 64 * 8;  // shorts per w1 half (bf16 split)
    const size_t W2PN = (size_t)64 * 64 * 64 * 8;   // shorts per w2 half
    const size_t UPN  = (size_t)256 * 32 * 64 * 8;  // shorts: f16-u slot / f16-w1 slot
    const size_t DTWN = 32768;                      // floats, packed dt weights
    size_t used_small = (size_t)(ps - (char*)d_ws);
    bool wonce = ws_size >= used_small + 2 * sizeof(unsigned short) * (W1PN + W2PN);
    bool upack = ws_size >= used_small + 2 * sizeof(unsigned short) * (W1PN + W2PN + UPN)
                           + sizeof(float) * DTWN;

    unsigned short *w1ph, *w1pl, *w2ph, *w2pl;
    unsigned short *uf = nullptr, *w1f = nullptr;
    float* dtw = nullptr;
    if (wonce) {
        w1ph = (unsigned short*)ps;
        w1pl = w1ph + W1PN;
        w2ph = w1pl + W1PN;
        w2pl = w2ph + W2PN;
        if (!upack)
            pack_split<5, 1><<<2112, 256, 0, stream>>>(in_w, 1024, w1ph, w1pl);
        pack_split<6, 0><<<1024, 256, 0, stream>>>(out_w, 2048, w2ph, w2pl);
        if (upack) {
            uf  = w2pl + W2PN;            // f16 u (per batch), 4M shorts
            w1f = uf + UPN;               // f16 w1 rows 0..4095, 4M shorts
            dtw = (float*)(w1f + UPN);
            pack_f16<5><<<2048, 256, 0, stream>>>(in_w, w1f);
            pack_dtw<<<128, 256, 0, stream>>>(in_w, dtw);
        }
    } else {
        w1ph = (unsigned short*)R2;
        w1pl = w1ph + W1PN;
        w2ph = (unsigned short*)R2;
        w2pl = w2ph + W2PN;
    }

    for (int b = 0; b < 4; b++) {
        const float* ub = u + (size_t)b * 4096 * 1024;
        const float* rb = reward + (size_t)b * 4096;
        float* ob = out + (size_t)b * 4096 * 1024;

        if (!wonce)
            pack_split<5, 1><<<2112, 256, 0, stream>>>(in_w, 1024, w1ph, w1pl);
        // 1) in_proj
        if (upack) {
            pack_f16<5><<<2048, 256, 0, stream>>>(ub, uf);
            // main N=4096: fp16 1-pass 256^2, grid 256 = 1/CU
            gemm256h<32, 32><<<256, 512, 0, stream>>>(uf, w1f, in_b, z, xc);
            // dt columns (32): coalesced fp32 dot kernel
            dtproj2<<<512, 256, 0, stream>>>(ub, dtw, in_b, dtraw);
        } else {
            mfma_gemm<0, 0, 1024, 1, 0><<<1056, 256, 0, stream>>>(
                ub, nullptr, nullptr, w1ph, w1pl, in_b, z, xc, dtraw, nullptr);
        }
        // 2) conv + local chunk scan (xc -> ylocal in R2)
        scanA<<<2048, 64, 0, stream>>>(xc, dtraw, rb, conv_w, conv_b,
                                       dt_bias, A_log, bw, bb,
                                       ylocal, decay, Fb, Eb);
        // 3) cross-chunk scan
        scanB<<<32, 64, 0, stream>>>(Fb, Eb, Sprev);
        // 4) gate + carried state -> y fragment-packed into R1
        passC<<<8192, 256, 0, stream>>>(ylocal, z, Sprev, decay, yph, ypl);
        if (!wonce)
            pack_split<6, 0><<<1024, 256, 0, stream>>>(out_w, 2048, w2ph, w2pl);
        // 5) out_proj (bf16x3, split-K=4; partials into dead z (R0) + ylocal)
        if (upack) {
            float* pA = z;
            float* pB = z + (size_t)4096 * 1024;
            float* pC = ylocal;
            gemm256<64, 16, 1><<<256, 512, 0, stream>>>(
                yph, ypl, w2ph, w2pl, nullptr, nullptr, nullptr,
                ob, pA, pB, pC);
            addOut4<<<4096, 256, 0, stream>>>(ob, pA, pB, pC);
        } else {
            mfma_gemm<1, 1, 2048, 2, 0><<<512, 256, 0, stream>>>(
                nullptr, yph, ypl, w2ph, w2pl, nullptr,
                z, nullptr, nullptr, ob);
            addOut<<<4096, 256, 0, stream>>>(ob, z);
        }
    }
}

// Round 6
// 801.345 us; speedup vs baseline: 1.5805x; 1.1794x over previous
//
#include <hip/hip_runtime.h>
#include <hip/hip_bf16.h>
#include <math.h>

// D_MODEL=1024, D_INNER=2048, NHEADS=32, HEADDIM=64, CHUNK=64, B=4, L=4096
// C == ones collapses the state dim -> scalar scan per (h,p) channel.
//
// R6: out_proj switched to fp16x1 (mirrors R5's validated in_proj change):
// per K-tile/wave MFMA 96->32, LDS 128->64KB, staging 8->4 loads. passC now
// emits a SINGLE fp16 fragment-packed operand (store traffic halved); w2
// packed once as fp16. bf16x3 gemm256 deleted (fallback tiers keep the old
// LDS-free mfma_gemm). Error budget: out_proj fp16 adds ~4e-4 abs on O(1)
// outputs vs absmax 0.0156 headroom.
//
// ws tiers (runtime-checked, deterministic):
//  small  ~100.3 MB : old layout, weights packed per batch, A split in-reg
//  +25.7  ~126.0 MB : weights packed once per call (bf16x3 fallback GEMMs)
//  +16.9  ~142.9 MB : f16 packs -> gemm256h in/out + dtproj2 path

typedef __attribute__((ext_vector_type(8))) short bf16x8;
typedef __attribute__((ext_vector_type(8))) _Float16 f16x8;
typedef __attribute__((ext_vector_type(4))) float f32x4;

__device__ __forceinline__ float bf2f(unsigned short u) {
    union { float f; unsigned int i; } x; x.i = ((unsigned int)u) << 16; return x.f;
}
__device__ __forceinline__ unsigned short f2bf(float f) {  // RNE
    union { float f; unsigned int i; } x; x.f = f;
    unsigned int r = x.i + 0x7fffu + ((x.i >> 16) & 1u);
    return (unsigned short)(r >> 16);
}
__device__ __forceinline__ unsigned short f2h(float f) {   // fp16 RNE bits
    _Float16 h = (_Float16)f;
    unsigned short u; __builtin_memcpy(&u, &h, 2); return u;
}
__device__ __forceinline__ float softplusf(float x) {
    return (x > 20.f) ? x : log1pf(expf(x));
}
__device__ __forceinline__ float silu_mod(float x) {  // sigmoid(x)+0.1x per ref
    return 1.f / (1.f + expf(-x)) + 0.1f * x;
}
__device__ __forceinline__ void cvt_split2(float x, float y,
                                           unsigned int* hi, unsigned int* lo) {
    __hip_bfloat162 h2 = __float22bfloat162_rn(make_float2(x, y));
    unsigned int h; __builtin_memcpy(&h, &h2, 4);
    union { float f; unsigned int i; } fx, fy;
    fx.i = h << 16;
    fy.i = h & 0xffff0000u;
    __hip_bfloat162 l2 = __float22bfloat162_rn(make_float2(x - fx.f, y - fy.f));
    unsigned int l; __builtin_memcpy(&l, &l2, 4);
    *hi = h; *lo = l;
}
__device__ __forceinline__ void split4(float4 v, ushort4* h, ushort4* l) {
    unsigned short t;
    t = f2bf(v.x); h->x = t; l->x = f2bf(v.x - bf2f(t));
    t = f2bf(v.y); h->y = t; l->y = f2bf(v.y - bf2f(t));
    t = f2bf(v.z); h->z = t; l->z = f2bf(v.z - bf2f(t));
    t = f2bf(v.w); h->w = t; l->w = f2bf(v.w - bf2f(t));
}

// ---------------------------------------------------------------------------
// pack row-major fp32 -> fragment-order split bf16 (fallback tiers).
// thread t -> (tile = t>>(6+KCN_LOG), kc = (t>>6)&(KCN-1), lane = t&63):
//   data = src[tile*16 + (lane&15)][kc*32 + (lane>>4)*8 .. +8]
// REMAP (in_w): row<4096 -> row; 4096..4127 -> row+128 (dt cols); else zero.
// ---------------------------------------------------------------------------
template <int KCN_LOG, int REMAP>
__global__ __launch_bounds__(256) void pack_split(
    const float* __restrict__ src, int src_ld,
    unsigned short* __restrict__ h, unsigned short* __restrict__ l)
{
    int t = blockIdx.x * 256 + threadIdx.x;
    int lane = t & 63;
    int kc = (t >> 6) & ((1 << KCN_LOG) - 1);
    int tile = t >> (6 + KCN_LOG);
    int n = tile * 16 + (lane & 15);
    int k = kc * 32 + (lane >> 4) * 8;
    int sr = n;
    if (REMAP) sr = (n < 4096) ? n : (n < 4128 ? n + 128 : -1);
    float4 v0 = make_float4(0.f, 0.f, 0.f, 0.f), v1 = v0;
    if (sr >= 0) {
        const float* s = src + (size_t)sr * src_ld + k;
        v0 = *(const float4*)s;
        v1 = *(const float4*)(s + 4);
    }
    ushort4 h0, l0, h1, l1;
    split4(v0, &h0, &l0);
    split4(v1, &h1, &l1);
    size_t o = (size_t)t * 8;
    *(ushort4*)(h + o) = h0; *(ushort4*)(h + o + 4) = h1;
    *(ushort4*)(l + o) = l0; *(ushort4*)(l + o + 4) = l1;
}

// ---------------------------------------------------------------------------
// pack_f16: row-major fp32 -> fragment-order fp16 (single copy). Same
// thread->element mapping as pack_split. src_ld = 32<<KCN_LOG.
// ---------------------------------------------------------------------------
template <int KCN_LOG>
__global__ __launch_bounds__(256) void pack_f16(
    const float* __restrict__ src, unsigned short* __restrict__ d)
{
    int t = blockIdx.x * 256 + threadIdx.x;
    int lane = t & 63;
    int kc = (t >> 6) & ((1 << KCN_LOG) - 1);
    int tile = t >> (6 + KCN_LOG);
    int n = tile * 16 + (lane & 15);
    int k = kc * 32 + (lane >> 4) * 8;
    const float* s = src + (size_t)n * (32 << KCN_LOG) + k;
    float4 v0 = *(const float4*)s;
    float4 v1 = *(const float4*)(s + 4);
    ushort4 h0, h1;
    h0.x = f2h(v0.x); h0.y = f2h(v0.y); h0.z = f2h(v0.z); h0.w = f2h(v0.w);
    h1.x = f2h(v1.x); h1.y = f2h(v1.y); h1.z = f2h(v1.z); h1.w = f2h(v1.w);
    size_t o = (size_t)t * 8;
    *(ushort4*)(d + o) = h0; *(ushort4*)(d + o + 4) = h1;
}

// ---------------------------------------------------------------------------
// pack_dtw: dt weight rows 4224..4255 of in_w -> dtw[k4][h][4] fp32 (128 KB),
// so dtproj2's 32-lane h-groups read contiguous 512B. Once per call.
// ---------------------------------------------------------------------------
__global__ __launch_bounds__(256) void pack_dtw(
    const float* __restrict__ in_w, float* __restrict__ dtw)
{
    int o = blockIdx.x * 256 + threadIdx.x;   // 32768
    int k4 = o >> 7, rem = o & 127;
    int h = rem >> 2, r = rem & 3;
    dtw[o] = in_w[(size_t)(4224 + h) * 1024 + k4 * 4 + r];
}

// ---------------------------------------------------------------------------
// dtproj2: dtraw[l,h] = dot(u[l,:], dt_w[h,:]) + in_b[4224+h], fp32.
// ---------------------------------------------------------------------------
__global__ __launch_bounds__(256) void dtproj2(
    const float* __restrict__ u, const float* __restrict__ dtw,
    const float* __restrict__ in_b, float* __restrict__ dtraw)
{
    int idx = blockIdx.x * 256 + threadIdx.x;
    int l = idx >> 5, h = idx & 31;
    const float* ur = u + (size_t)l * 1024;
    const float* wp = dtw + h * 4;
    float s0 = 0.f, s1 = 0.f, s2 = 0.f, s3 = 0.f;
#pragma unroll 4
    for (int k4 = 0; k4 < 256; k4++) {
        float4 a = *(const float4*)(ur + k4 * 4);
        float4 b = *(const float4*)(wp + (size_t)k4 * 128);
        s0 += a.x * b.x; s1 += a.y * b.y;
        s2 += a.z * b.z; s3 += a.w * b.w;
    }
    dtraw[idx] = (s0 + s1) + (s2 + s3) + in_b[4224 + h];
}

// ---------------------------------------------------------------------------
// LDS-free bf16x3 MFMA NT-GEMM (old structure) — kept for fallback tiers.
// ---------------------------------------------------------------------------
template <int ASRC, int OUT, int KDIM, int KSPLIT, int NOFF>
__global__ __launch_bounds__(256, 2) void mfma_gemm(
    const float* __restrict__ Af,
    const unsigned short* __restrict__ Aph, const unsigned short* __restrict__ Apl,
    const unsigned short* __restrict__ Bph, const unsigned short* __restrict__ Bpl,
    const float* __restrict__ bias,
    float* __restrict__ oz, float* __restrict__ oxc,
    float* __restrict__ dtraw, float* __restrict__ outC)
{
    constexpr int KCN = KDIM / 32;       // layout stride (total K chunks)
    constexpr int KCNL = KCN / KSPLIT;   // chunks this block iterates
    const int g = blockIdx.x;
    const int ks = (KSPLIT > 1) ? (g >> 8) : 0;
    const int gg = (KSPLIT > 1) ? (g & 255) : g;
    const int m0 = ((gg & 7) * 4 + ((gg >> 3) & 3)) * 128;
    const int n0 = (gg >> 5) * 128 + NOFF;
    const int tid = threadIdx.x;
    const int lane = tid & 63, w = tid >> 6;
    const int wm = w & 1, wn = w >> 1;
    const int fr = lane & 15, q = lane >> 4;
    const size_t koff = (size_t)ks * KCNL * 512;  // shorts

    const unsigned short* bhp[4];
    const unsigned short* blp[4];
#pragma unroll
    for (int nt = 0; nt < 4; nt++) {
        size_t c = ((size_t)((n0 >> 4) + wn * 4 + nt) * KCN * 64 + lane) * 8 + koff;
        bhp[nt] = Bph + c;
        blp[nt] = Bpl + c;
    }
    const float* afp[4];
    const unsigned short* ahp[4];
    const unsigned short* alp[4];
#pragma unroll
    for (int mt = 0; mt < 4; mt++) {
        if (ASRC == 0) {
            afp[mt] = Af + (size_t)(m0 + wm * 64 + mt * 16 + fr) * KDIM + q * 8
                         + (size_t)ks * (KDIM / KSPLIT);
        } else {
            size_t c = ((size_t)((m0 >> 4) + wm * 4 + mt) * KCN * 64 + lane) * 8 + koff;
            ahp[mt] = Aph + c;
            alp[mt] = Apl + c;
        }
    }

    f32x4 acc[4][4];
#pragma unroll
    for (int i = 0; i < 4; i++)
#pragma unroll
        for (int j = 0; j < 4; j++) acc[i][j] = (f32x4){0.f, 0.f, 0.f, 0.f};

    bf16x8 bh[2][4], bl[2][4], ah[2][4], al[2][4];
    float4 af0[2][4], af1[2][4];

#define LOAD_STEP(B)                                                          \
    {                                                                         \
        _Pragma("unroll") for (int nt = 0; nt < 4; nt++) {                    \
            bh[B][nt] = *(const bf16x8*)bhp[nt];                              \
            bl[B][nt] = *(const bf16x8*)blp[nt];                              \
            bhp[nt] += 512; blp[nt] += 512;                                   \
        }                                                                     \
        _Pragma("unroll") for (int mt = 0; mt < 4; mt++) {                    \
            if (ASRC == 1) {                                                  \
                ah[B][mt] = *(const bf16x8*)ahp[mt];                          \
                al[B][mt] = *(const bf16x8*)alp[mt];                          \
                ahp[mt] += 512; alp[mt] += 512;                               \
            } else {                                                          \
                af0[B][mt] = *(const float4*)afp[mt];                         \
                af1[B][mt] = *(const float4*)(afp[mt] + 4);                   \
                afp[mt] += 32;                                                \
            }                                                                 \
        }                                                                     \
    }

#define MFMA_STEP(B)                                                          \
    {                                                                         \
        bf16x8 xah[4], xal[4];                                                \
        _Pragma("unroll") for (int mt = 0; mt < 4; mt++) {                    \
            if (ASRC == 1) {                                                  \
                xah[mt] = ah[B][mt]; xal[mt] = al[B][mt];                     \
            } else {                                                          \
                union { bf16x8 v; unsigned int u[4]; } H, L;                  \
                cvt_split2(af0[B][mt].x, af0[B][mt].y, &H.u[0], &L.u[0]);     \
                cvt_split2(af0[B][mt].z, af0[B][mt].w, &H.u[1], &L.u[1]);     \
                cvt_split2(af1[B][mt].x, af1[B][mt].y, &H.u[2], &L.u[2]);     \
                cvt_split2(af1[B][mt].z, af1[B][mt].w, &H.u[3], &L.u[3]);     \
                xah[mt] = H.v; xal[mt] = L.v;                                 \
            }                                                                 \
        }                                                                     \
        _Pragma("unroll") for (int mt = 0; mt < 4; mt++)                      \
            _Pragma("unroll") for (int nt = 0; nt < 4; nt++)                  \
                acc[mt][nt] = __builtin_amdgcn_mfma_f32_16x16x32_bf16(        \
                    xah[mt], bh[B][nt], acc[mt][nt], 0, 0, 0);                \
        _Pragma("unroll") for (int mt = 0; mt < 4; mt++)                      \
            _Pragma("unroll") for (int nt = 0; nt < 4; nt++)                  \
                acc[mt][nt] = __builtin_amdgcn_mfma_f32_16x16x32_bf16(        \
                    xah[mt], bl[B][nt], acc[mt][nt], 0, 0, 0);                \
        _Pragma("unroll") for (int mt = 0; mt < 4; mt++)                      \
            _Pragma("unroll") for (int nt = 0; nt < 4; nt++)                  \
                acc[mt][nt] = __builtin_amdgcn_mfma_f32_16x16x32_bf16(        \
                    xal[mt], bh[B][nt], acc[mt][nt], 0, 0, 0);                \
    }

    LOAD_STEP(0);
    for (int kc = 0; kc + 2 < KCNL; kc += 2) {
        LOAD_STEP(1);
        MFMA_STEP(0);
        LOAD_STEP(0);
        MFMA_STEP(1);
    }
    LOAD_STEP(1);
    MFMA_STEP(0);
    MFMA_STEP(1);
#undef LOAD_STEP
#undef MFMA_STEP

    // epilogue: D[row=q*4+reg][col=fr] per 16x16 tile
#pragma unroll
    for (int nt = 0; nt < 4; nt++) {
        int jn = n0 + wn * 64 + nt * 16 + fr;
        if (OUT == 0 && jn >= 4128) continue;
        float bv = 0.f;
        if (OUT == 0) bv = bias[jn < 4096 ? jn : jn + 128];
#pragma unroll
        for (int mt = 0; mt < 4; mt++) {
#pragma unroll
            for (int reg = 0; reg < 4; reg++) {
                int rm = m0 + wm * 64 + mt * 16 + q * 4 + reg;
                float v = acc[mt][nt][reg] + bv;
                if (OUT == 0) {
                    if (jn < 2048)      oz[(size_t)rm * 2048 + jn] = v;
                    else if (jn < 4096) oxc[(size_t)rm * 2048 + (jn - 2048)] = v;
                    else                dtraw[(size_t)rm * 32 + (jn - 4096)] = v;
                } else {
                    float* dst = (KSPLIT == 1 || ks == 0) ? outC : oz;
                    dst[(size_t)rm * 1024 + jn] = v;
                }
            }
        }
    }
}

// ---------------------------------------------------------------------------
// gemm256h: fp16 single-pass 256x256 GEMM. 512 threads (8 waves, 2M x 4N),
// BK=32. LDS 64KB: 2 buf x (A 16KB + B 16KB) fragment order (ds_read_b128
// stride-1: conflict-free). Per K-tile/wave: 4 gload_lds stage(k+1),
// 12 ds_read, 32 MFMA. Simple 2-barrier loop (R2-R4: schedule-insensitive).
// OUT 0: in_proj main (N=4096, XCD-swizzled, +bias -> z/xc).
// OUT 1: out_proj split-K=4 (ks=g>>6; slice 0 -> outC, 1..3 -> p1..p3).
// ---------------------------------------------------------------------------
template <int KCN, int NT, int OUT>
__global__ __launch_bounds__(512, 2) void gemm256h(
    const unsigned short* __restrict__ Ap, const unsigned short* __restrict__ Bp,
    const float* __restrict__ bias,
    float* __restrict__ oz, float* __restrict__ oxc,
    float* __restrict__ outC,
    float* __restrict__ p1, float* __restrict__ p2, float* __restrict__ p3)
{
    __shared__ unsigned short smem[32768];  // 64 KiB
    const int g = blockIdx.x;
    int mb, nb, kt0;
    float* dst = outC;
    if (OUT == 0) {
        const int xcd = g & 7, loc = g >> 3;  // XCD x owns n-blocks {2x,2x+1}
        nb = xcd * 2 + (loc & 1);
        mb = loc >> 1;
        kt0 = 0;
    } else {
        const int ks = g >> 6, loc = g & 63;
        mb = loc & 15; nb = loc >> 4; kt0 = ks * NT;
        dst = (ks == 0) ? outC : (ks == 1 ? p1 : (ks == 2 ? p2 : p3));
    }
    const int tid = threadIdx.x;
    const int lane = tid & 63, w = tid >> 6;
    const int wm = w & 1, wn = w >> 1;
    const int fr = lane & 15, q = lane >> 4;

    // per-wave staging: A tiles {2w,2w+1}, B tiles {2w,2w+1} (4 gload_lds)
    const unsigned short* gp[4];
    {
        const int tA0 = mb * 16 + 2 * w;
        const int tB0 = nb * 16 + 2 * w;
        gp[0] = Ap + ((size_t)tA0 * KCN + kt0) * 512 + lane * 8;
        gp[1] = Ap + ((size_t)(tA0 + 1) * KCN + kt0) * 512 + lane * 8;
        gp[2] = Bp + ((size_t)tB0 * KCN + kt0) * 512 + lane * 8;
        gp[3] = Bp + ((size_t)(tB0 + 1) * KCN + kt0) * 512 + lane * 8;
    }
    int ldso[4];
    {
        const int t0 = 2 * w * 512, t1 = t0 + 512;
        ldso[0] = t0;         ldso[1] = t1;          // A
        ldso[2] = 8192 + t0;  ldso[3] = 8192 + t1;   // B
    }

#define STAGE(BUF)                                                            \
    {                                                                         \
        unsigned short* bp = smem + (BUF) * 16384;                            \
        _Pragma("unroll") for (int i = 0; i < 4; i++) {                       \
            __builtin_amdgcn_global_load_lds(                                 \
                (const __attribute__((address_space(1))) unsigned int*)gp[i], \
                (__attribute__((address_space(3))) unsigned int*)(bp + ldso[i]), \
                16, 0, 0);                                                    \
            gp[i] += 512;                                                     \
        }                                                                     \
    }

    f32x4 acc[8][4];
#pragma unroll
    for (int i = 0; i < 8; i++)
#pragma unroll
        for (int j = 0; j < 4; j++) acc[i][j] = (f32x4){0.f, 0.f, 0.f, 0.f};

    STAGE(0);
    __syncthreads();
    for (int kt = 0; kt < NT; ++kt) {
        const int cur = kt & 1;
        if (kt + 1 < NT) STAGE(cur ^ 1);
        const unsigned short* sb = smem + cur * 16384;
        f16x8 Bv[4];
#pragma unroll
        for (int nt = 0; nt < 4; nt++)
            Bv[nt] = *(const f16x8*)(sb + 8192 + (wn * 4 + nt) * 512 + lane * 8);
#pragma unroll
        for (int mt = 0; mt < 8; mt++) {
            f16x8 av = *(const f16x8*)(sb + (wm * 8 + mt) * 512 + lane * 8);
            __builtin_amdgcn_s_setprio(1);
#pragma unroll
            for (int nt = 0; nt < 4; nt++)
                acc[mt][nt] = __builtin_amdgcn_mfma_f32_16x16x32_f16(
                    av, Bv[nt], acc[mt][nt], 0, 0, 0);
            __builtin_amdgcn_s_setprio(0);
        }
        __syncthreads();
    }
#undef STAGE

    // epilogue: D[row=q*4+reg][col=fr] per 16x16 tile
    const int m0 = mb * 256, n0 = nb * 256;
#pragma unroll
    for (int nt = 0; nt < 4; nt++) {
        const int jn = n0 + wn * 64 + nt * 16 + fr;
        float bv = 0.f;
        if (OUT == 0) bv = bias[jn];
#pragma unroll
        for (int mt = 0; mt < 8; mt++) {
#pragma unroll
            for (int reg = 0; reg < 4; reg++) {
                const int rm = m0 + wm * 128 + mt * 16 + q * 4 + reg;
                float v = acc[mt][nt][reg] + bv;
                if (OUT == 0) {
                    if (jn < 2048) oz[(size_t)rm * 2048 + jn] = v;
                    else           oxc[(size_t)rm * 2048 + (jn - 2048)] = v;
                } else {
                    dst[(size_t)rm * 1024 + jn] = v;
                }
            }
        }
    }
}

// ---------------------------------------------------------------------------
// split-K reductions.
// ---------------------------------------------------------------------------
__global__ __launch_bounds__(256) void addOut(
    float* __restrict__ dst, const float* __restrict__ part)
{
    size_t i = ((size_t)blockIdx.x * 256 + threadIdx.x) * 4;
    float4 a = *(const float4*)(dst + i);
    float4 b = *(const float4*)(part + i);
    a.x += b.x; a.y += b.y; a.z += b.z; a.w += b.w;
    *(float4*)(dst + i) = a;
}

__global__ __launch_bounds__(256) void addOut4(
    float* __restrict__ dst, const float* __restrict__ a,
    const float* __restrict__ b, const float* __restrict__ c)
{
    size_t i = ((size_t)blockIdx.x * 256 + threadIdx.x) * 4;
    float4 d = *(const float4*)(dst + i);
    float4 x = *(const float4*)(a + i);
    float4 y = *(const float4*)(b + i);
    float4 zz = *(const float4*)(c + i);
    d.x += x.x + y.x + zz.x;
    d.y += x.y + y.y + zz.y;
    d.z += x.z + y.z + zz.z;
    d.w += x.w + y.w + zz.w;
    *(float4*)(dst + i) = d;
}

// ---------------------------------------------------------------------------
// scanA: one batch. Per (h, chunk) block, 64 threads (p). conv4 + silu' +
// softplus(dt) + decay cumsum + 64-step local scan. xc/ylocal fp32.
// ---------------------------------------------------------------------------
__global__ __launch_bounds__(64) void scanA(
    const float* __restrict__ xc,
    const float* __restrict__ dtraw, const float* __restrict__ reward,
    const float* __restrict__ conv_w, const float* __restrict__ conv_b,
    const float* __restrict__ dt_bias, const float* __restrict__ A_log,
    const float* __restrict__ bw, const float* __restrict__ bb,
    float* __restrict__ ylocal,
    float* __restrict__ decay, float* __restrict__ Fb, float* __restrict__ Eb)
{
    const int blk = blockIdx.x;        // h*64 + t
    const int t = blk & 63;
    const int h = blk >> 6;
    const int p = threadIdx.x;
    const int l0 = t * 64;

    __shared__ float xs[67][65];
    __shared__ float gbuf[64], ebuf[64], dtbuf[64];
    __shared__ float cum63;

    float v1 = bw[p] + bw[p + 64];
    float v2 = bb[p] + bb[p + 64];
#pragma unroll
    for (int o = 32; o > 0; o >>= 1) {
        v1 += __shfl_down(v1, o, 64);
        v2 += __shfl_down(v2, o, 64);
    }
    const float sbw = __shfl(v1, 0, 64);
    const float sbb = __shfl(v2, 0, 64);

    const int l = l0 + p;
    const float dt = softplusf(dtraw[(size_t)l * 32 + h] + dt_bias[h]);
    const float a = -expf(A_log[h]) * dt;
    float cum = a;
#pragma unroll
    for (int o = 1; o < 64; o <<= 1) {
        float uo = __shfl_up(cum, o, 64);
        if (p >= o) cum += uo;
    }
    decay[(size_t)l * 32 + h] = expf(cum);
    gbuf[p] = reward[l] * sbw + sbb;
    ebuf[p] = expf(a);
    dtbuf[p] = dt;
    if (p == 63) cum63 = cum;

    const int c = h * 64 + p;
    for (int r = 0; r < 67; r++) {
        int ls = l0 - 3 + r;
        xs[r][p] = (ls >= 0) ? xc[(size_t)ls * 2048 + c] : 0.f;
    }
    __syncthreads();

    const float w0 = conv_w[c * 4 + 0], w1 = conv_w[c * 4 + 1],
                w2 = conv_w[c * 4 + 2], w3 = conv_w[c * 4 + 3];
    const float cb = conv_b[c];
    float y = 0.f;
    float* outp = ylocal + (size_t)l0 * 2048 + c;
#pragma unroll 4
    for (int i = 0; i < 64; i++) {
        float v = cb + xs[i][p] * w0 + xs[i + 1][p] * w1 +
                  xs[i + 2][p] * w2 + xs[i + 3][p] * w3;
        float xdt = silu_mod(v) * dtbuf[i];
        y = y * ebuf[i] + gbuf[i] * xdt;
        outp[(size_t)i * 2048] = y;
    }
    Fb[((size_t)h * 64 + t) * 64 + p] = y;
    if (p == 0) Eb[(size_t)h * 64 + t] = expf(cum63);
}

// ---------------------------------------------------------------------------
// scanB: cross-chunk scan. 32 blocks x 64 threads.
// ---------------------------------------------------------------------------
__global__ __launch_bounds__(64) void scanB(
    const float* __restrict__ Fb, const float* __restrict__ Eb,
    float* __restrict__ Sprev)
{
    int idx = blockIdx.x * blockDim.x + threadIdx.x;  // 2048
    int p = idx & 63;
    int h = idx >> 6;
    int base = h * 64;
    float S = 0.f;
#pragma unroll 8
    for (int t = 0; t < 64; t++) {
        Sprev[(size_t)(base + t) * 64 + p] = S;
        S = S * Eb[base + t] + Fb[(size_t)(base + t) * 64 + p];
    }
}

// ---------------------------------------------------------------------------
// passC: y = (ylocal + S*decay) * silu_mod(z), emitted as SINGLE fp16 in
// gemm2's A fragment-packed order (KCN=64). (R6: was split bf16 x2.)
// ---------------------------------------------------------------------------
__global__ __launch_bounds__(256) void passC(
    const float* __restrict__ yl, const float* __restrict__ z,
    const float* __restrict__ Sprev, const float* __restrict__ decay,
    unsigned short* __restrict__ ypf)
{
    size_t idx = ((size_t)blockIdx.x * 256 + threadIdx.x) * 4;
    int row = (int)(idx >> 11);
    int cc = (int)(idx & 2047);
    int t = row >> 6;
    int h = cc >> 6, p = cc & 63;
    float4 av = *(const float4*)(yl + idx);
    float4 bvz = *(const float4*)(z + idx);
    float4 sv = *(const float4*)(Sprev + ((size_t)(h * 64 + t)) * 64 + p);
    float d = decay[(size_t)row * 32 + h];
    float4 yv;
    yv.x = (av.x + sv.x * d) * silu_mod(bvz.x);
    yv.y = (av.y + sv.y * d) * silu_mod(bvz.y);
    yv.z = (av.z + sv.z * d) * silu_mod(bvz.z);
    yv.w = (av.w + sv.w * d) * silu_mod(bvz.w);
    ushort4 hv;
    hv.x = f2h(yv.x); hv.y = f2h(yv.y); hv.z = f2h(yv.z); hv.w = f2h(yv.w);
    size_t chunk = (((size_t)(row >> 4) * 64 + (cc >> 5)) * 64) + ((cc >> 3) & 3) * 16 + (row & 15);
    size_t o = chunk * 8 + (cc & 7);
    *(ushort4*)(ypf + o) = hv;
}

// ---------------------------------------------------------------------------
// passC_bf (fallback tiers): split bf16 x2 emit, as before.
// ---------------------------------------------------------------------------
__global__ __launch_bounds__(256) void passC_bf(
    const float* __restrict__ yl, const float* __restrict__ z,
    const float* __restrict__ Sprev, const float* __restrict__ decay,
    unsigned short* __restrict__ yph, unsigned short* __restrict__ ypl)
{
    size_t idx = ((size_t)blockIdx.x * 256 + threadIdx.x) * 4;
    int row = (int)(idx >> 11);
    int cc = (int)(idx & 2047);
    int t = row >> 6;
    int h = cc >> 6, p = cc & 63;
    float4 av = *(const float4*)(yl + idx);
    float4 bvz = *(const float4*)(z + idx);
    float4 sv = *(const float4*)(Sprev + ((size_t)(h * 64 + t)) * 64 + p);
    float d = decay[(size_t)row * 32 + h];
    float4 yv;
    yv.x = (av.x + sv.x * d) * silu_mod(bvz.x);
    yv.y = (av.y + sv.y * d) * silu_mod(bvz.y);
    yv.z = (av.z + sv.z * d) * silu_mod(bvz.z);
    yv.w = (av.w + sv.w * d) * silu_mod(bvz.w);
    ushort4 hv, lv;
    split4(yv, &hv, &lv);
    size_t chunk = (((size_t)(row >> 4) * 64 + (cc >> 5)) * 64) + ((cc >> 3) & 3) * 16 + (row & 15);
    size_t o = chunk * 8 + (cc & 7);
    *(ushort4*)(yph + o) = hv;
    *(ushort4*)(ypl + o) = lv;
}

// ---------------------------------------------------------------------------
extern "C" void kernel_launch(void* const* d_in, const int* in_sizes, int n_in,
                              void* d_out, int out_size, void* d_ws, size_t ws_size,
                              hipStream_t stream)
{
    const float* u       = (const float*)d_in[0];
    const float* reward  = (const float*)d_in[1];
    const float* in_w    = (const float*)d_in[2];
    const float* in_b    = (const float*)d_in[3];
    const float* conv_w  = (const float*)d_in[4];
    const float* conv_b  = (const float*)d_in[5];
    const float* bw      = (const float*)d_in[6];
    const float* bb      = (const float*)d_in[7];
    const float* dt_bias = (const float*)d_in[8];
    const float* A_log   = (const float*)d_in[9];
    const float* out_w   = (const float*)d_in[10];
    float* out = (float*)d_out;

    char* p = (char*)d_ws;
    const size_t SEG = (size_t)4096 * 2048 * 4;  // 33,554,432 B
    float* z = (float*)p;                              // R0 (-> split-K partials)
    float* xc = (float*)(p + SEG);                     // R1 (-> ypacked)
    unsigned short* yph = (unsigned short*)(p + SEG);
    unsigned short* ypl = yph + (size_t)4096 * 2048;
    char* R2 = p + 2 * SEG;                            // R2
    float* ylocal = (float*)R2;
    char* ps = p + 3 * SEG;                            // tail
    float* dtraw = (float*)ps;                 ps += (size_t)4096 * 32 * 4;
    float* decay = (float*)ps;                 ps += (size_t)4096 * 32 * 4;
    float* Fb    = (float*)ps;                 ps += (size_t)32 * 64 * 64 * 4;
    float* Eb    = (float*)ps;                 ps += (size_t)32 * 64 * 4;
    float* Sprev = (float*)ps;                 ps += (size_t)32 * 64 * 64 * 4;

    const size_t W1PN = (size_t)264 * 32 * 64 * 8;  // shorts per w1 half (bf16 split)
    const size_t W2PN = (size_t)64 * 64 * 64 * 8;   // shorts per w2 half
    const size_t UPN  = (size_t)256 * 32 * 64 * 8;  // shorts: f16-u slot / f16-w1 slot
    const size_t DTWN = 32768;                      // floats, packed dt weights
    size_t used_small = (size_t)(ps - (char*)d_ws);
    bool wonce = ws_size >= used_small + 2 * sizeof(unsigned short) * (W1PN + W2PN);
    bool upack = ws_size >= used_small + 2 * sizeof(unsigned short) * (W1PN + W2PN + UPN)
                           + sizeof(float) * DTWN;

    unsigned short *w1ph, *w1pl, *w2ph, *w2pl;
    unsigned short *uf = nullptr, *w1f = nullptr, *w2f = nullptr;
    float* dtw = nullptr;
    if (wonce) {
        w1ph = (unsigned short*)ps;
        w1pl = w1ph + W1PN;
        w2ph = w1pl + W1PN;
        w2pl = w2ph + W2PN;
        if (!upack) {
            pack_split<5, 1><<<2112, 256, 0, stream>>>(in_w, 1024, w1ph, w1pl);
            pack_split<6, 0><<<1024, 256, 0, stream>>>(out_w, 2048, w2ph, w2pl);
        } else {
            w2f = w2ph;                   // f16 w2 (single) reuses w2ph slot
            uf  = w2pl + W2PN;            // f16 u (per batch), 4M shorts
            w1f = uf + UPN;               // f16 w1 rows 0..4095, 4M shorts
            dtw = (float*)(w1f + UPN);
            pack_f16<6><<<1024, 256, 0, stream>>>(out_w, w2f);
            pack_f16<5><<<2048, 256, 0, stream>>>(in_w, w1f);
            pack_dtw<<<128, 256, 0, stream>>>(in_w, dtw);
        }
    } else {
        w1ph = (unsigned short*)R2;
        w1pl = w1ph + W1PN;
        w2ph = (unsigned short*)R2;
        w2pl = w2ph + W2PN;
    }

    for (int b = 0; b < 4; b++) {
        const float* ub = u + (size_t)b * 4096 * 1024;
        const float* rb = reward + (size_t)b * 4096;
        float* ob = out + (size_t)b * 4096 * 1024;

        if (!wonce)
            pack_split<5, 1><<<2112, 256, 0, stream>>>(in_w, 1024, w1ph, w1pl);
        // 1) in_proj
        if (upack) {
            pack_f16<5><<<2048, 256, 0, stream>>>(ub, uf);
            // main N=4096: fp16 1-pass 256^2, grid 256 = 1/CU
            gemm256h<32, 32, 0><<<256, 512, 0, stream>>>(
                uf, w1f, in_b, z, xc, nullptr, nullptr, nullptr, nullptr);
            // dt columns (32): coalesced fp32 dot kernel
            dtproj2<<<512, 256, 0, stream>>>(ub, dtw, in_b, dtraw);
        } else {
            mfma_gemm<0, 0, 1024, 1, 0><<<1056, 256, 0, stream>>>(
                ub, nullptr, nullptr, w1ph, w1pl, in_b, z, xc, dtraw, nullptr);
        }
        // 2) conv + local chunk scan (xc -> ylocal in R2)
        scanA<<<2048, 64, 0, stream>>>(xc, dtraw, rb, conv_w, conv_b,
                                       dt_bias, A_log, bw, bb,
                                       ylocal, decay, Fb, Eb);
        // 3) cross-chunk scan
        scanB<<<32, 64, 0, stream>>>(Fb, Eb, Sprev);
        // 4) gate + carried state -> y packed into R1
        if (upack) {
            passC<<<8192, 256, 0, stream>>>(ylocal, z, Sprev, decay, yph);
        } else {
            passC_bf<<<8192, 256, 0, stream>>>(ylocal, z, Sprev, decay, yph, ypl);
        }
        if (!wonce)
            pack_split<6, 0><<<1024, 256, 0, stream>>>(out_w, 2048, w2ph, w2pl);
        // 5) out_proj
        if (upack) {
            // fp16 split-K=4: 256 blocks; partials into dead z (R0) + ylocal
            float* pA = z;
            float* pB = z + (size_t)4096 * 1024;
            float* pC = ylocal;
            gemm256h<64, 16, 1><<<256, 512, 0, stream>>>(
                yph, w2f, nullptr, nullptr, nullptr, ob, pA, pB, pC);
            addOut4<<<4096, 256, 0, stream>>>(ob, pA, pB, pC);
        } else {
            mfma_gemm<1, 1, 2048, 2, 0><<<512, 256, 0, stream>>>(
                nullptr, yph, ypl, w2ph, w2pl, nullptr,
                z, nullptr, nullptr, ob);
            addOut<<<4096, 256, 0, stream>>>(ob, z);
        }
    }
}